// Round 3
// baseline (3924.661 us; speedup 1.0000x reference)
//
#include <hip/hip_runtime.h>

#define ND 128   // node feature dim D
#define ED 32    // edge radial basis dim
#define LN_EPS 1e-5f

// ---------------------------------------------------------------------------
// Detect int64-vs-int32 edge_index, convert to int32 ctr/ngh, histogram ctr.
// ---------------------------------------------------------------------------
__global__ void conv_hist_kernel(const unsigned* __restrict__ raw,
                                 int* __restrict__ ctr, int* __restrict__ ngh,
                                 int* __restrict__ cnt, int E) {
    __shared__ int s_is64;
    if (threadIdx.x == 0) {
        unsigned acc = 0;
        for (int i = 1; i < 512; i += 2) acc |= raw[i];
        s_is64 = (acc == 0) ? 1 : 0;
    }
    __syncthreads();
    const int is64 = s_is64;
    const int tid = blockIdx.x * blockDim.x + threadIdx.x;
    const int stride = gridDim.x * blockDim.x;
    if (is64) {
        for (int e = tid; e < E; e += stride) {
            const int c = (int)raw[(size_t)2 * e];
            ctr[e] = c;
            ngh[e] = (int)raw[(size_t)2 * E + (size_t)2 * e];
            atomicAdd(&cnt[c], 1);
        }
    } else {
        for (int e = tid; e < E; e += stride) {
            const int c = (int)raw[e];
            ctr[e] = c;
            ngh[e] = (int)raw[(size_t)E + e];
            atomicAdd(&cnt[c], 1);
        }
    }
}

// ---------------------------------------------------------------------------
// Single-block exclusive scan over cnt[0..N) -> base[0..N]; zero cur[].
// ---------------------------------------------------------------------------
__global__ __launch_bounds__(1024) void scan_kernel(
    const int* __restrict__ cnt, int* __restrict__ base,
    int* __restrict__ cur, int N) {
    __shared__ int part[1024];
    const int tid = threadIdx.x;
    const int chunk = (N + 1023) >> 10;
    const int lo = tid * chunk;
    const int hi = min(lo + chunk, N);
    int s = 0;
    for (int i = lo; i < hi; ++i) { s += cnt[i]; cur[i] = 0; }
    part[tid] = s;
    __syncthreads();
    for (int off = 1; off < 1024; off <<= 1) {
        int v = 0;
        if (tid >= off) v = part[tid - off];
        __syncthreads();
        part[tid] += v;
        __syncthreads();
    }
    int excl = (tid > 0) ? part[tid - 1] : 0;
    for (int i = lo; i < hi; ++i) { base[i] = excl; excl += cnt[i]; }
    if (tid == 1023) base[N] = part[1023];
}

// ---------------------------------------------------------------------------
// Scatter edges into center-sorted order as int2 (edge_id, neighbor).
// ---------------------------------------------------------------------------
__global__ void scatter_kernel(const int* __restrict__ ctr,
                               const int* __restrict__ ngh,
                               const int* __restrict__ base,
                               int* __restrict__ cur,
                               int2* __restrict__ epair, int E) {
    const int tid = blockIdx.x * blockDim.x + threadIdx.x;
    const int stride = gridDim.x * blockDim.x;
    for (int e = tid; e < E; e += stride) {
        const int c = ctr[e];
        const int pos = base[c] + atomicAdd(&cur[c], 1);
        epair[pos] = make_int2(e, ngh[e]);
    }
}

// ---------------------------------------------------------------------------
// wcc = W_center_node @ W_concat[0:128, :]
// ---------------------------------------------------------------------------
__global__ void wcc_kernel(const float* __restrict__ Wc,
                           const float* __restrict__ Wcat,
                           float* __restrict__ wcc) {
    const int i = blockIdx.x;
    const int j = threadIdx.x;
    float acc = 0.f;
    for (int k = 0; k < ND; ++k)
        acc += Wc[i * ND + k] * Wcat[k * ND + j];
    wcc[i * ND + j] = acc;
}

// ---------------------------------------------------------------------------
// out[M,128] = A[M,128] @ W[128,128], fp32. W in LDS. Each 32-lane slot owns
// 2 consecutive rows (16 rows per 256-thread block step); A rows stream
// through registers in 32-float chunks with 1-chunk-ahead prefetch. One
// ds_read_b128 of W feeds 8 FMAs (2 rows x 4 cols).
// ---------------------------------------------------------------------------
__global__ __launch_bounds__(256) void gemm128_kernel(
    const float* __restrict__ A, const float* __restrict__ W,
    float* __restrict__ out, int M) {
    __shared__ float Ws[ND * ND];
    for (int i = threadIdx.x; i < ND * ND; i += 256) Ws[i] = W[i];
    __syncthreads();
    const int slot = threadIdx.x >> 5;
    const int j0 = (threadIdx.x & 31) * 4;
    for (int r0 = blockIdx.x * 16; r0 < M; r0 += gridDim.x * 16) {
        const int rA = r0 + slot * 2;
        const int rB = rA + 1;
        const bool vA = rA < M, vB = rB < M;
        const float4* pa = (const float4*)(A + (size_t)rA * ND);
        const float4* pb = (const float4*)(A + (size_t)rB * ND);
        float4 a0[8], a1[8], b0[8], b1[8];   // ping-pong chunk buffers
        const float4 z4 = {0.f, 0.f, 0.f, 0.f};
#pragma unroll
        for (int i = 0; i < 8; ++i) { a0[i] = vA ? pa[i] : z4; b0[i] = vB ? pb[i] : z4; }
        float4 acc0 = z4, acc1 = z4;
#pragma unroll
        for (int c = 0; c < 4; ++c) {
            if (c < 3) {
                const int off = (c + 1) * 8;
                if ((c & 1) == 0) {
#pragma unroll
                    for (int i = 0; i < 8; ++i) {
                        a1[i] = vA ? pa[off + i] : z4;
                        b1[i] = vB ? pb[off + i] : z4;
                    }
                } else {
#pragma unroll
                    for (int i = 0; i < 8; ++i) {
                        a0[i] = vA ? pa[off + i] : z4;
                        b0[i] = vB ? pb[off + i] : z4;
                    }
                }
            }
            const float* ca = (const float*)((c & 1) ? a1 : a0);
            const float* cb = (const float*)((c & 1) ? b1 : b0);
#pragma unroll
            for (int k2 = 0; k2 < 32; ++k2) {
                const float4 w = *(const float4*)&Ws[(c * 32 + k2) * ND + j0];
                const float x = ca[k2], y = cb[k2];
                acc0.x += x * w.x; acc0.y += x * w.y;
                acc0.z += x * w.z; acc0.w += x * w.w;
                acc1.x += y * w.x; acc1.y += y * w.y;
                acc1.z += y * w.z; acc1.w += y * w.w;
            }
        }
        if (vA) *(float4*)&out[(size_t)rA * ND + j0] = acc0;
        if (vB) *(float4*)&out[(size_t)rB * ND + j0] = acc1;
    }
}

// ---------------------------------------------------------------------------
// Segmented edge reduction, LDS-free: W_edge columns live in 128 VGPRs.
// One 32-lane half-wave per node; 3-stage pipeline (idx 2-ahead, data
// 1-ahead ping-pong). No atomics, single coalesced row write.
// ---------------------------------------------------------------------------
__device__ __forceinline__ void seg_load(const float* __restrict__ edge_attr,
                                         const float* __restrict__ P,
                                         int e, int n, int j0,
                                         float4 (&ea)[8], float4& pr) {
    const float4* ea4 = (const float4*)(edge_attr + (size_t)e * ED);
#pragma unroll
    for (int i = 0; i < 8; ++i) ea[i] = ea4[i];
    pr = *(const float4*)&P[(size_t)n * ND + j0];
}

__device__ __forceinline__ void seg_comp(const float4 (&ea)[8], const float4& pr,
                                         const float4 (&w)[ED], float4& acc) {
    float4 r = {0.f, 0.f, 0.f, 0.f};
#pragma unroll
    for (int k = 0; k < ED; ++k) {
        const float a = ((const float*)ea)[k];
        r.x += a * w[k].x; r.y += a * w[k].y;
        r.z += a * w[k].z; r.w += a * w[k].w;
    }
    acc.x += r.x * pr.x; acc.y += r.y * pr.y;
    acc.z += r.z * pr.z; acc.w += r.w * pr.w;
}

__global__ __launch_bounds__(256, 2) void seg_kernel(
    const int* __restrict__ base, const int2* __restrict__ epair,
    const float* __restrict__ edge_attr, const float* __restrict__ W_edge,
    const float* __restrict__ P, float* __restrict__ m, int N) {
    const int j0 = (threadIdx.x & 31) * 4;
    float4 w[ED];
#pragma unroll
    for (int k = 0; k < ED; ++k)
        w[k] = *(const float4*)&W_edge[k * ND + j0];
    const int v = blockIdx.x * 8 + (threadIdx.x >> 5);
    int s = 0, t = 0;
    if (v < N) { s = base[v]; t = base[v + 1]; }
    float4 acc = {0.f, 0.f, 0.f, 0.f};

    int p = s;
    float4 eaA[8], eaB[8], pA, pB;
    int2 enN = make_int2(0, 0);
    if (p < t) {
        const int2 en0 = epair[p];
        seg_load(edge_attr, P, en0.x, en0.y, j0, eaA, pA);
    }
    if (p + 1 < t) enN = epair[p + 1];
    while (p + 1 < t) {
        seg_load(edge_attr, P, enN.x, enN.y, j0, eaB, pB);   // data p+1
        if (p + 2 < t) enN = epair[p + 2];                    // idx p+2
        seg_comp(eaA, pA, w, acc);                            // compute p
        ++p;
        if (p + 1 < t) {
            seg_load(edge_attr, P, enN.x, enN.y, j0, eaA, pA);
            if (p + 2 < t) enN = epair[p + 2];
            seg_comp(eaB, pB, w, acc);
            ++p;
        } else {
            seg_comp(eaB, pB, w, acc);
            ++p;
        }
    }
    if (p < t) seg_comp(eaA, pA, w, acc);
    if (v < N) *(float4*)&m[(size_t)v * ND + j0] = acc;
}

// ---------------------------------------------------------------------------
// out[r] = LayerNorm(C2[r] + m[r] @ W_bot) * lnw + lnb   (in-place on d_out)
// Same register-chunked structure as gemm128_kernel, 2 rows per slot.
// ---------------------------------------------------------------------------
__global__ __launch_bounds__(256) void final_kernel(
    const float* __restrict__ C2, const float* __restrict__ m,
    const float* __restrict__ Wb, const float* __restrict__ lnw,
    const float* __restrict__ lnb, float* __restrict__ out, int N) {
    __shared__ float Ws[ND * ND];
    for (int i = threadIdx.x; i < ND * ND; i += 256) Ws[i] = Wb[i];
    __syncthreads();
    const int slot = threadIdx.x >> 5;
    const int j0 = (threadIdx.x & 31) * 4;
    for (int r0 = blockIdx.x * 16; r0 < N; r0 += gridDim.x * 16) {
        const int rA = r0 + slot * 2;
        const int rB = rA + 1;
        const bool vA = rA < N, vB = rB < N;
        const float4* pa = (const float4*)(m + (size_t)rA * ND);
        const float4* pb = (const float4*)(m + (size_t)rB * ND);
        float4 a0[8], a1[8], b0[8], b1[8];
        const float4 z4 = {0.f, 0.f, 0.f, 0.f};
#pragma unroll
        for (int i = 0; i < 8; ++i) { a0[i] = vA ? pa[i] : z4; b0[i] = vB ? pb[i] : z4; }
        float4 acc0 = z4, acc1 = z4;
        if (vA) acc0 = *(const float4*)&C2[(size_t)rA * ND + j0];
        if (vB) acc1 = *(const float4*)&C2[(size_t)rB * ND + j0];
#pragma unroll
        for (int c = 0; c < 4; ++c) {
            if (c < 3) {
                const int off = (c + 1) * 8;
                if ((c & 1) == 0) {
#pragma unroll
                    for (int i = 0; i < 8; ++i) {
                        a1[i] = vA ? pa[off + i] : z4;
                        b1[i] = vB ? pb[off + i] : z4;
                    }
                } else {
#pragma unroll
                    for (int i = 0; i < 8; ++i) {
                        a0[i] = vA ? pa[off + i] : z4;
                        b0[i] = vB ? pb[off + i] : z4;
                    }
                }
            }
            const float* ca = (const float*)((c & 1) ? a1 : a0);
            const float* cb = (const float*)((c & 1) ? b1 : b0);
#pragma unroll
            for (int k2 = 0; k2 < 32; ++k2) {
                const float4 w = *(const float4*)&Ws[(c * 32 + k2) * ND + j0];
                const float x = ca[k2], y = cb[k2];
                acc0.x += x * w.x; acc0.y += x * w.y;
                acc0.z += x * w.z; acc0.w += x * w.w;
                acc1.x += y * w.x; acc1.y += y * w.y;
                acc1.z += y * w.z; acc1.w += y * w.w;
            }
        }
        const float4 w4 = *(const float4*)&lnw[j0];
        const float4 b4 = *(const float4*)&lnb[j0];
        // LN row rA (reduce across the 32 lanes of this half-wave)
        {
            float sum = acc0.x + acc0.y + acc0.z + acc0.w;
            sum += __shfl_xor(sum, 16); sum += __shfl_xor(sum, 8);
            sum += __shfl_xor(sum, 4);  sum += __shfl_xor(sum, 2);
            sum += __shfl_xor(sum, 1);
            const float mean = sum * (1.f / ND);
            const float4 d = {acc0.x - mean, acc0.y - mean,
                              acc0.z - mean, acc0.w - mean};
            float q = d.x * d.x + d.y * d.y + d.z * d.z + d.w * d.w;
            q += __shfl_xor(q, 16); q += __shfl_xor(q, 8);
            q += __shfl_xor(q, 4);  q += __shfl_xor(q, 2);
            q += __shfl_xor(q, 1);
            const float rstd = rsqrtf(q * (1.f / ND) + LN_EPS);
            if (vA) {
                float4 o;
                o.x = d.x * rstd * w4.x + b4.x;
                o.y = d.y * rstd * w4.y + b4.y;
                o.z = d.z * rstd * w4.z + b4.z;
                o.w = d.w * rstd * w4.w + b4.w;
                *(float4*)&out[(size_t)rA * ND + j0] = o;
            }
        }
        // LN row rB
        {
            float sum = acc1.x + acc1.y + acc1.z + acc1.w;
            sum += __shfl_xor(sum, 16); sum += __shfl_xor(sum, 8);
            sum += __shfl_xor(sum, 4);  sum += __shfl_xor(sum, 2);
            sum += __shfl_xor(sum, 1);
            const float mean = sum * (1.f / ND);
            const float4 d = {acc1.x - mean, acc1.y - mean,
                              acc1.z - mean, acc1.w - mean};
            float q = d.x * d.x + d.y * d.y + d.z * d.z + d.w * d.w;
            q += __shfl_xor(q, 16); q += __shfl_xor(q, 8);
            q += __shfl_xor(q, 4);  q += __shfl_xor(q, 2);
            q += __shfl_xor(q, 1);
            const float rstd = rsqrtf(q * (1.f / ND) + LN_EPS);
            if (vB) {
                float4 o;
                o.x = d.x * rstd * w4.x + b4.x;
                o.y = d.y * rstd * w4.y + b4.y;
                o.z = d.z * rstd * w4.z + b4.z;
                o.w = d.w * rstd * w4.w + b4.w;
                *(float4*)&out[(size_t)rB * ND + j0] = o;
            }
        }
    }
}

// ---------------------------------------------------------------------------
extern "C" void kernel_launch(void* const* d_in, const int* in_sizes, int n_in,
                              void* d_out, int out_size, void* d_ws, size_t ws_size,
                              hipStream_t stream) {
    const float*    node_attr = (const float*)d_in[0];
    const float*    edge_attr = (const float*)d_in[1];
    const unsigned* edge_idx  = (const unsigned*)d_in[2];
    const float*    W_node    = (const float*)d_in[3];
    const float*    W_center  = (const float*)d_in[4];
    const float*    W_concat  = (const float*)d_in[5];
    const float*    W_edge    = (const float*)d_in[6];
    const float*    lnw       = (const float*)d_in[7];
    const float*    lnb       = (const float*)d_in[8];
    float* out = (float*)d_out;

    const int N = in_sizes[0] / ND;   // 50000
    const int E = in_sizes[1] / ED;   // 800000

    char* ws = (char*)d_ws;
    float* wcc   = (float*)ws;                          // 16384 f
    float* P     = (float*)(ws + 65536);                // [N,128]
    float* m     = P + (size_t)N * ND;                  // [N,128]
    int*   ctr   = (int*)(m + (size_t)N * ND);          // [E]
    int*   ngh   = ctr + E;                             // [E]
    int2*  epair = (int2*)(ngh + E);                    // [E]
    int*   cnt   = (int*)(epair + E);                   // [N]
    int*   base  = cnt + N;                             // [N+1]
    int*   cur   = base + N + 1;                        // [N]

    hipMemsetAsync(cnt, 0, (size_t)N * sizeof(int), stream);
    conv_hist_kernel<<<512, 256, 0, stream>>>(edge_idx, ctr, ngh, cnt, E);
    scan_kernel<<<1, 1024, 0, stream>>>(cnt, base, cur, N);
    scatter_kernel<<<512, 256, 0, stream>>>(ctr, ngh, base, cur, epair, E);
    wcc_kernel<<<128, 128, 0, stream>>>(W_center, W_concat, wcc);
    gemm128_kernel<<<(N + 15) / 16, 256, 0, stream>>>(node_attr, W_node, P, N);
    gemm128_kernel<<<(N + 15) / 16, 256, 0, stream>>>(node_attr, wcc, out, N);
    seg_kernel<<<(N + 7) / 8, 256, 0, stream>>>(base, epair, edge_attr, W_edge,
                                                P, m, N);
    final_kernel<<<(N + 15) / 16, 256, 0, stream>>>(out, m, W_concat + ND * ND,
                                                    lnw, lnb, out, N);
}

// Round 4
// 2538.537 us; speedup vs baseline: 1.5460x; 1.5460x over previous
//
#include <hip/hip_runtime.h>

#define ND 128   // node feature dim D
#define ED 32    // edge radial basis dim
#define LN_EPS 1e-5f

// ---------------------------------------------------------------------------
// Detect int64-vs-int32 edge_index, convert to int32 ctr/ngh, histogram ctr.
// ---------------------------------------------------------------------------
__global__ void conv_hist_kernel(const unsigned* __restrict__ raw,
                                 int* __restrict__ ctr, int* __restrict__ ngh,
                                 int* __restrict__ cnt, int E) {
    __shared__ int s_is64;
    if (threadIdx.x == 0) {
        unsigned acc = 0;
        for (int i = 1; i < 512; i += 2) acc |= raw[i];
        s_is64 = (acc == 0) ? 1 : 0;
    }
    __syncthreads();
    const int is64 = s_is64;
    const int tid = blockIdx.x * blockDim.x + threadIdx.x;
    const int stride = gridDim.x * blockDim.x;
    if (is64) {
        for (int e = tid; e < E; e += stride) {
            const int c = (int)raw[(size_t)2 * e];
            ctr[e] = c;
            ngh[e] = (int)raw[(size_t)2 * E + (size_t)2 * e];
            atomicAdd(&cnt[c], 1);
        }
    } else {
        for (int e = tid; e < E; e += stride) {
            const int c = (int)raw[e];
            ctr[e] = c;
            ngh[e] = (int)raw[(size_t)E + e];
            atomicAdd(&cnt[c], 1);
        }
    }
}

// ---------------------------------------------------------------------------
// Single-block exclusive scan over cnt[0..N) -> base[0..N]; zero cur[].
// ---------------------------------------------------------------------------
__global__ __launch_bounds__(1024) void scan_kernel(
    const int* __restrict__ cnt, int* __restrict__ base,
    int* __restrict__ cur, int N) {
    __shared__ int part[1024];
    const int tid = threadIdx.x;
    const int chunk = (N + 1023) >> 10;
    const int lo = tid * chunk;
    const int hi = min(lo + chunk, N);
    int s = 0;
    for (int i = lo; i < hi; ++i) { s += cnt[i]; cur[i] = 0; }
    part[tid] = s;
    __syncthreads();
    for (int off = 1; off < 1024; off <<= 1) {
        int v = 0;
        if (tid >= off) v = part[tid - off];
        __syncthreads();
        part[tid] += v;
        __syncthreads();
    }
    int excl = (tid > 0) ? part[tid - 1] : 0;
    for (int i = lo; i < hi; ++i) { base[i] = excl; excl += cnt[i]; }
    if (tid == 1023) base[N] = part[1023];
}

// ---------------------------------------------------------------------------
// Scatter edges into center-sorted order as int2 (edge_id, neighbor).
// ---------------------------------------------------------------------------
__global__ void scatter_kernel(const int* __restrict__ ctr,
                               const int* __restrict__ ngh,
                               const int* __restrict__ base,
                               int* __restrict__ cur,
                               int2* __restrict__ epair, int E) {
    const int tid = blockIdx.x * blockDim.x + threadIdx.x;
    const int stride = gridDim.x * blockDim.x;
    for (int e = tid; e < E; e += stride) {
        const int c = ctr[e];
        const int pos = base[c] + atomicAdd(&cur[c], 1);
        epair[pos] = make_int2(e, ngh[e]);
    }
}

// ---------------------------------------------------------------------------
// wcc = W_center_node @ W_concat[0:128, :]
// ---------------------------------------------------------------------------
__global__ void wcc_kernel(const float* __restrict__ Wc,
                           const float* __restrict__ Wcat,
                           float* __restrict__ wcc) {
    const int i = blockIdx.x;
    const int j = threadIdx.x;
    float acc = 0.f;
    for (int k = 0; k < ND; ++k)
        acc += Wc[i * ND + k] * Wcat[k * ND + j];
    wcc[i * ND + j] = acc;
}

// ---------------------------------------------------------------------------
// out[M,128] = A[M,128] @ W[128,128], fp32. W in LDS (64 KB). Each 32-lane
// slot owns 4 rows (32 rows/block-step); one ds_read_b128 of W[k] feeds
// 16 FMAs. A values via same-addr global loads (L1 broadcast), double-
// buffered with a statically-unrolled ping-pong (NO runtime pointer select —
// that spilled to scratch in the previous version).
// ---------------------------------------------------------------------------
__global__ __launch_bounds__(256) void gemm128_kernel(
    const float* __restrict__ A, const float* __restrict__ W,
    float* __restrict__ out, int M) {
    __shared__ float Ws[ND * ND];
    {
        float4* d = (float4*)Ws;
        const float4* s = (const float4*)W;
        for (int i = threadIdx.x; i < (ND * ND) / 4; i += 256) d[i] = s[i];
    }
    __syncthreads();
    const int slot = threadIdx.x >> 5;
    const int j0 = (threadIdx.x & 31) * 4;
    for (int r0 = blockIdx.x * 32; r0 < M; r0 += gridDim.x * 32) {
        const int rbase = r0 + slot * 4;
        int rr[4]; bool vv[4];
#pragma unroll
        for (int q = 0; q < 4; ++q) {
            const int r = rbase + q;
            vv[q] = (r < M);
            rr[q] = vv[q] ? r : (M - 1);
        }
        float4 acc[4] = {{0,0,0,0},{0,0,0,0},{0,0,0,0},{0,0,0,0}};
        float4 aA[4], aB[4];
#pragma unroll
        for (int q = 0; q < 4; ++q)
            aA[q] = *(const float4*)&A[(size_t)rr[q] * ND + 0];
#pragma unroll
        for (int c = 0; c < 32; c += 2) {
            if (c + 1 < 32) {
#pragma unroll
                for (int q = 0; q < 4; ++q)
                    aB[q] = *(const float4*)&A[(size_t)rr[q] * ND + (c + 1) * 4];
            }
#pragma unroll
            for (int kk = 0; kk < 4; ++kk) {
                const int k = c * 4 + kk;
                const float4 w = *(const float4*)&Ws[k * ND + j0];
#pragma unroll
                for (int q = 0; q < 4; ++q) {
                    const float a = ((const float*)&aA[q])[kk];
                    acc[q].x += a * w.x; acc[q].y += a * w.y;
                    acc[q].z += a * w.z; acc[q].w += a * w.w;
                }
            }
            if (c + 2 < 32) {
#pragma unroll
                for (int q = 0; q < 4; ++q)
                    aA[q] = *(const float4*)&A[(size_t)rr[q] * ND + (c + 2) * 4];
            }
#pragma unroll
            for (int kk = 0; kk < 4; ++kk) {
                const int k = (c + 1) * 4 + kk;
                const float4 w = *(const float4*)&Ws[k * ND + j0];
#pragma unroll
                for (int q = 0; q < 4; ++q) {
                    const float a = ((const float*)&aB[q])[kk];
                    acc[q].x += a * w.x; acc[q].y += a * w.y;
                    acc[q].z += a * w.z; acc[q].w += a * w.w;
                }
            }
        }
#pragma unroll
        for (int q = 0; q < 4; ++q)
            if (vv[q]) *(float4*)&out[(size_t)rr[q] * ND + j0] = acc[q];
    }
}

// ---------------------------------------------------------------------------
// Segmented edge reduction, LDS-free: W_edge columns live in 128 VGPRs.
// One 32-lane half-wave per node; 3-stage pipeline (idx 2-ahead, data
// 1-ahead ping-pong). No atomics, single coalesced row write.
// ---------------------------------------------------------------------------
__device__ __forceinline__ void seg_load(const float* __restrict__ edge_attr,
                                         const float* __restrict__ P,
                                         int e, int n, int j0,
                                         float4 (&ea)[8], float4& pr) {
    const float4* ea4 = (const float4*)(edge_attr + (size_t)e * ED);
#pragma unroll
    for (int i = 0; i < 8; ++i) ea[i] = ea4[i];
    pr = *(const float4*)&P[(size_t)n * ND + j0];
}

__device__ __forceinline__ void seg_comp(const float4 (&ea)[8], const float4& pr,
                                         const float4 (&w)[ED], float4& acc) {
    float4 r = {0.f, 0.f, 0.f, 0.f};
#pragma unroll
    for (int k = 0; k < ED; ++k) {
        const float a = ((const float*)ea)[k];
        r.x += a * w[k].x; r.y += a * w[k].y;
        r.z += a * w[k].z; r.w += a * w[k].w;
    }
    acc.x += r.x * pr.x; acc.y += r.y * pr.y;
    acc.z += r.z * pr.z; acc.w += r.w * pr.w;
}

__global__ __launch_bounds__(256, 2) void seg_kernel(
    const int* __restrict__ base, const int2* __restrict__ epair,
    const float* __restrict__ edge_attr, const float* __restrict__ W_edge,
    const float* __restrict__ P, float* __restrict__ m, int N) {
    const int j0 = (threadIdx.x & 31) * 4;
    float4 w[ED];
#pragma unroll
    for (int k = 0; k < ED; ++k)
        w[k] = *(const float4*)&W_edge[k * ND + j0];
    const int v = blockIdx.x * 8 + (threadIdx.x >> 5);
    int s = 0, t = 0;
    if (v < N) { s = base[v]; t = base[v + 1]; }
    float4 acc = {0.f, 0.f, 0.f, 0.f};

    int p = s;
    float4 eaA[8], eaB[8], pA, pB;
    int2 enN = make_int2(0, 0);
    if (p < t) {
        const int2 en0 = epair[p];
        seg_load(edge_attr, P, en0.x, en0.y, j0, eaA, pA);
    }
    if (p + 1 < t) enN = epair[p + 1];
    while (p + 1 < t) {
        seg_load(edge_attr, P, enN.x, enN.y, j0, eaB, pB);   // data p+1
        if (p + 2 < t) enN = epair[p + 2];                    // idx p+2
        seg_comp(eaA, pA, w, acc);                            // compute p
        ++p;
        if (p + 1 < t) {
            seg_load(edge_attr, P, enN.x, enN.y, j0, eaA, pA);
            if (p + 2 < t) enN = epair[p + 2];
            seg_comp(eaB, pB, w, acc);
            ++p;
        } else {
            seg_comp(eaB, pB, w, acc);
            ++p;
        }
    }
    if (p < t) seg_comp(eaA, pA, w, acc);
    if (v < N) *(float4*)&m[(size_t)v * ND + j0] = acc;
}

// ---------------------------------------------------------------------------
// out[r] = LayerNorm(C2[r] + m[r] @ W_bot) * lnw + lnb   (in-place on d_out)
// Same structure as gemm128_kernel; C2 added in the epilogue.
// ---------------------------------------------------------------------------
__global__ __launch_bounds__(256) void final_kernel(
    const float* __restrict__ C2, const float* __restrict__ m,
    const float* __restrict__ Wb, const float* __restrict__ lnw,
    const float* __restrict__ lnb, float* __restrict__ out, int N) {
    __shared__ float Ws[ND * ND];
    {
        float4* d = (float4*)Ws;
        const float4* s = (const float4*)Wb;
        for (int i = threadIdx.x; i < (ND * ND) / 4; i += 256) d[i] = s[i];
    }
    __syncthreads();
    const int slot = threadIdx.x >> 5;
    const int j0 = (threadIdx.x & 31) * 4;
    for (int r0 = blockIdx.x * 32; r0 < N; r0 += gridDim.x * 32) {
        const int rbase = r0 + slot * 4;
        int rr[4]; bool vv[4];
#pragma unroll
        for (int q = 0; q < 4; ++q) {
            const int r = rbase + q;
            vv[q] = (r < N);
            rr[q] = vv[q] ? r : (N - 1);
        }
        float4 acc[4] = {{0,0,0,0},{0,0,0,0},{0,0,0,0},{0,0,0,0}};
        float4 aA[4], aB[4];
#pragma unroll
        for (int q = 0; q < 4; ++q)
            aA[q] = *(const float4*)&m[(size_t)rr[q] * ND + 0];
#pragma unroll
        for (int c = 0; c < 32; c += 2) {
            if (c + 1 < 32) {
#pragma unroll
                for (int q = 0; q < 4; ++q)
                    aB[q] = *(const float4*)&m[(size_t)rr[q] * ND + (c + 1) * 4];
            }
#pragma unroll
            for (int kk = 0; kk < 4; ++kk) {
                const int k = c * 4 + kk;
                const float4 w = *(const float4*)&Ws[k * ND + j0];
#pragma unroll
                for (int q = 0; q < 4; ++q) {
                    const float a = ((const float*)&aA[q])[kk];
                    acc[q].x += a * w.x; acc[q].y += a * w.y;
                    acc[q].z += a * w.z; acc[q].w += a * w.w;
                }
            }
            if (c + 2 < 32) {
#pragma unroll
                for (int q = 0; q < 4; ++q)
                    aA[q] = *(const float4*)&m[(size_t)rr[q] * ND + (c + 2) * 4];
            }
#pragma unroll
            for (int kk = 0; kk < 4; ++kk) {
                const int k = (c + 1) * 4 + kk;
                const float4 w = *(const float4*)&Ws[k * ND + j0];
#pragma unroll
                for (int q = 0; q < 4; ++q) {
                    const float a = ((const float*)&aB[q])[kk];
                    acc[q].x += a * w.x; acc[q].y += a * w.y;
                    acc[q].z += a * w.z; acc[q].w += a * w.w;
                }
            }
        }
        const float4 w4 = *(const float4*)&lnw[j0];
        const float4 b4 = *(const float4*)&lnb[j0];
#pragma unroll
        for (int q = 0; q < 4; ++q) {
            const float4 c2 = *(const float4*)&C2[(size_t)rr[q] * ND + j0];
            float4 h = {acc[q].x + c2.x, acc[q].y + c2.y,
                        acc[q].z + c2.z, acc[q].w + c2.w};
            float sum = h.x + h.y + h.z + h.w;
            sum += __shfl_xor(sum, 16); sum += __shfl_xor(sum, 8);
            sum += __shfl_xor(sum, 4);  sum += __shfl_xor(sum, 2);
            sum += __shfl_xor(sum, 1);
            const float mean = sum * (1.f / ND);
            const float4 d = {h.x - mean, h.y - mean, h.z - mean, h.w - mean};
            float qv = d.x * d.x + d.y * d.y + d.z * d.z + d.w * d.w;
            qv += __shfl_xor(qv, 16); qv += __shfl_xor(qv, 8);
            qv += __shfl_xor(qv, 4);  qv += __shfl_xor(qv, 2);
            qv += __shfl_xor(qv, 1);
            const float rstd = rsqrtf(qv * (1.f / ND) + LN_EPS);
            if (vv[q]) {
                float4 o;
                o.x = d.x * rstd * w4.x + b4.x;
                o.y = d.y * rstd * w4.y + b4.y;
                o.z = d.z * rstd * w4.z + b4.z;
                o.w = d.w * rstd * w4.w + b4.w;
                *(float4*)&out[(size_t)rr[q] * ND + j0] = o;
            }
        }
    }
}

// ---------------------------------------------------------------------------
extern "C" void kernel_launch(void* const* d_in, const int* in_sizes, int n_in,
                              void* d_out, int out_size, void* d_ws, size_t ws_size,
                              hipStream_t stream) {
    const float*    node_attr = (const float*)d_in[0];
    const float*    edge_attr = (const float*)d_in[1];
    const unsigned* edge_idx  = (const unsigned*)d_in[2];
    const float*    W_node    = (const float*)d_in[3];
    const float*    W_center  = (const float*)d_in[4];
    const float*    W_concat  = (const float*)d_in[5];
    const float*    W_edge    = (const float*)d_in[6];
    const float*    lnw       = (const float*)d_in[7];
    const float*    lnb       = (const float*)d_in[8];
    float* out = (float*)d_out;

    const int N = in_sizes[0] / ND;   // 50000
    const int E = in_sizes[1] / ED;   // 800000

    char* ws = (char*)d_ws;
    float* wcc   = (float*)ws;                          // 16384 f
    float* P     = (float*)(ws + 65536);                // [N,128]
    float* m     = P + (size_t)N * ND;                  // [N,128]
    int*   ctr   = (int*)(m + (size_t)N * ND);          // [E]
    int*   ngh   = ctr + E;                             // [E]
    int2*  epair = (int2*)(ngh + E);                    // [E]
    int*   cnt   = (int*)(epair + E);                   // [N]
    int*   base  = cnt + N;                             // [N+1]
    int*   cur   = base + N + 1;                        // [N]

    hipMemsetAsync(cnt, 0, (size_t)N * sizeof(int), stream);
    conv_hist_kernel<<<512, 256, 0, stream>>>(edge_idx, ctr, ngh, cnt, E);
    scan_kernel<<<1, 1024, 0, stream>>>(cnt, base, cur, N);
    scatter_kernel<<<512, 256, 0, stream>>>(ctr, ngh, base, cur, epair, E);
    wcc_kernel<<<128, 128, 0, stream>>>(W_center, W_concat, wcc);
    gemm128_kernel<<<(N + 31) / 32, 256, 0, stream>>>(node_attr, W_node, P, N);
    gemm128_kernel<<<(N + 31) / 32, 256, 0, stream>>>(node_attr, wcc, out, N);
    seg_kernel<<<(N + 7) / 8, 256, 0, stream>>>(base, epair, edge_attr, W_edge,
                                                P, m, N);
    final_kernel<<<(N + 31) / 32, 256, 0, stream>>>(out, m, W_concat + ND * ND,
                                                    lnw, lnb, out, N);
}

// Round 5
// 647.970 us; speedup vs baseline: 6.0569x; 3.9177x over previous
//
#include <hip/hip_runtime.h>

#define ND 128   // node feature dim D
#define ED 32    // edge radial basis dim
#define LN_EPS 1e-5f

// ---------------------------------------------------------------------------
// Detect int64-vs-int32 edge_index, convert to int32 ctr/ngh, histogram ctr.
// ---------------------------------------------------------------------------
__global__ void conv_hist_kernel(const unsigned* __restrict__ raw,
                                 int* __restrict__ ctr, int* __restrict__ ngh,
                                 int* __restrict__ cnt, int E) {
    __shared__ int s_is64;
    if (threadIdx.x == 0) {
        unsigned acc = 0;
        for (int i = 1; i < 512; i += 2) acc |= raw[i];
        s_is64 = (acc == 0) ? 1 : 0;
    }
    __syncthreads();
    const int is64 = s_is64;
    const int tid = blockIdx.x * blockDim.x + threadIdx.x;
    const int stride = gridDim.x * blockDim.x;
    if (is64) {
        for (int e = tid; e < E; e += stride) {
            const int c = (int)raw[(size_t)2 * e];
            ctr[e] = c;
            ngh[e] = (int)raw[(size_t)2 * E + (size_t)2 * e];
            atomicAdd(&cnt[c], 1);
        }
    } else {
        for (int e = tid; e < E; e += stride) {
            const int c = (int)raw[e];
            ctr[e] = c;
            ngh[e] = (int)raw[(size_t)E + e];
            atomicAdd(&cnt[c], 1);
        }
    }
}

// ---------------------------------------------------------------------------
// Single-block exclusive scan over cnt[0..N) -> base[0..N]; zero cur[].
// ---------------------------------------------------------------------------
__global__ __launch_bounds__(1024) void scan_kernel(
    const int* __restrict__ cnt, int* __restrict__ base,
    int* __restrict__ cur, int N) {
    __shared__ int part[1024];
    const int tid = threadIdx.x;
    const int chunk = (N + 1023) >> 10;
    const int lo = tid * chunk;
    const int hi = min(lo + chunk, N);
    int s = 0;
    for (int i = lo; i < hi; ++i) { s += cnt[i]; cur[i] = 0; }
    part[tid] = s;
    __syncthreads();
    for (int off = 1; off < 1024; off <<= 1) {
        int v = 0;
        if (tid >= off) v = part[tid - off];
        __syncthreads();
        part[tid] += v;
        __syncthreads();
    }
    int excl = (tid > 0) ? part[tid - 1] : 0;
    for (int i = lo; i < hi; ++i) { base[i] = excl; excl += cnt[i]; }
    if (tid == 1023) base[N] = part[1023];
}

// ---------------------------------------------------------------------------
// Scatter edges into center-sorted order as int2 (edge_id, neighbor).
// ---------------------------------------------------------------------------
__global__ void scatter_kernel(const int* __restrict__ ctr,
                               const int* __restrict__ ngh,
                               const int* __restrict__ base,
                               int* __restrict__ cur,
                               int2* __restrict__ epair, int E) {
    const int tid = blockIdx.x * blockDim.x + threadIdx.x;
    const int stride = gridDim.x * blockDim.x;
    for (int e = tid; e < E; e += stride) {
        const int c = ctr[e];
        const int pos = base[c] + atomicAdd(&cur[c], 1);
        epair[pos] = make_int2(e, ngh[e]);
    }
}

// ---------------------------------------------------------------------------
// wcc = W_center_node @ W_concat[0:128, :]
// ---------------------------------------------------------------------------
__global__ void wcc_kernel(const float* __restrict__ Wc,
                           const float* __restrict__ Wcat,
                           float* __restrict__ wcc) {
    const int i = blockIdx.x;
    const int j = threadIdx.x;
    float acc = 0.f;
    for (int k = 0; k < ND; ++k)
        acc += Wc[i * ND + k] * Wcat[k * ND + j];
    wcc[i * ND + j] = acc;
}

// ---------------------------------------------------------------------------
// out[M,128] = A[M,128] @ W[128,128], fp32. W in LDS (64 KB). 512 threads =
// 16 slots of 32 lanes; each slot owns 4 consecutive rows; lane owns 4 cols.
// One ds_read_b128 of W[k] feeds 16 FMAs (VALU-bound). Rolled c-loop, named
// scalars only — the fully-unrolled ping-pong versions spilled to scratch
// (VGPR=256, 1.9 GB scratch traffic). Keep it simple; compiler schedules.
// ---------------------------------------------------------------------------
__global__ __launch_bounds__(512, 4) void gemm128_kernel(
    const float* __restrict__ A, const float* __restrict__ W,
    float* __restrict__ out, int M) {
    __shared__ float Ws[ND * ND];
    {
        float4* d = (float4*)Ws;
        const float4* s = (const float4*)W;
        for (int i = threadIdx.x; i < (ND * ND) / 4; i += 512) d[i] = s[i];
    }
    __syncthreads();
    const int slot = (int)(threadIdx.x >> 5);    // 0..15
    const int j0 = ((int)threadIdx.x & 31) * 4;
    const int rbase = blockIdx.x * 64 + slot * 4;
    const int r0 = (rbase + 0 < M) ? rbase + 0 : M - 1;
    const int r1 = (rbase + 1 < M) ? rbase + 1 : M - 1;
    const int r2 = (rbase + 2 < M) ? rbase + 2 : M - 1;
    const int r3 = (rbase + 3 < M) ? rbase + 3 : M - 1;
    const float* ap0 = A + (size_t)r0 * ND;
    const float* ap1 = A + (size_t)r1 * ND;
    const float* ap2 = A + (size_t)r2 * ND;
    const float* ap3 = A + (size_t)r3 * ND;
    float4 acc0 = {0,0,0,0}, acc1 = {0,0,0,0};
    float4 acc2 = {0,0,0,0}, acc3 = {0,0,0,0};
#pragma unroll 2
    for (int c = 0; c < 32; ++c) {
        const float4 a0 = *(const float4*)(ap0 + c * 4);
        const float4 a1 = *(const float4*)(ap1 + c * 4);
        const float4 a2 = *(const float4*)(ap2 + c * 4);
        const float4 a3 = *(const float4*)(ap3 + c * 4);
#pragma unroll
        for (int kk = 0; kk < 4; ++kk) {
            const float4 w = *(const float4*)&Ws[(c * 4 + kk) * ND + j0];
            const float x0 = ((const float*)&a0)[kk];
            const float x1 = ((const float*)&a1)[kk];
            const float x2 = ((const float*)&a2)[kk];
            const float x3 = ((const float*)&a3)[kk];
            acc0.x += x0 * w.x; acc0.y += x0 * w.y;
            acc0.z += x0 * w.z; acc0.w += x0 * w.w;
            acc1.x += x1 * w.x; acc1.y += x1 * w.y;
            acc1.z += x1 * w.z; acc1.w += x1 * w.w;
            acc2.x += x2 * w.x; acc2.y += x2 * w.y;
            acc2.z += x2 * w.z; acc2.w += x2 * w.w;
            acc3.x += x3 * w.x; acc3.y += x3 * w.y;
            acc3.z += x3 * w.z; acc3.w += x3 * w.w;
        }
    }
    if (rbase + 0 < M) *(float4*)&out[(size_t)r0 * ND + j0] = acc0;
    if (rbase + 1 < M) *(float4*)&out[(size_t)r1 * ND + j0] = acc1;
    if (rbase + 2 < M) *(float4*)&out[(size_t)r2 * ND + j0] = acc2;
    if (rbase + 3 < M) *(float4*)&out[(size_t)r3 * ND + j0] = acc3;
}

// ---------------------------------------------------------------------------
// Segmented edge reduction, LDS-free: W_edge columns live in 128 VGPRs.
// One 32-lane half-wave per node; 3-stage pipeline (idx 2-ahead, data
// 1-ahead ping-pong). No atomics, single coalesced row write.
// ---------------------------------------------------------------------------
__device__ __forceinline__ void seg_load(const float* __restrict__ edge_attr,
                                         const float* __restrict__ P,
                                         int e, int n, int j0,
                                         float4 (&ea)[8], float4& pr) {
    const float4* ea4 = (const float4*)(edge_attr + (size_t)e * ED);
#pragma unroll
    for (int i = 0; i < 8; ++i) ea[i] = ea4[i];
    pr = *(const float4*)&P[(size_t)n * ND + j0];
}

__device__ __forceinline__ void seg_comp(const float4 (&ea)[8], const float4& pr,
                                         const float4 (&w)[ED], float4& acc) {
    float4 r = {0.f, 0.f, 0.f, 0.f};
#pragma unroll
    for (int k = 0; k < ED; ++k) {
        const float a = ((const float*)ea)[k];
        r.x += a * w[k].x; r.y += a * w[k].y;
        r.z += a * w[k].z; r.w += a * w[k].w;
    }
    acc.x += r.x * pr.x; acc.y += r.y * pr.y;
    acc.z += r.z * pr.z; acc.w += r.w * pr.w;
}

__global__ __launch_bounds__(256, 2) void seg_kernel(
    const int* __restrict__ base, const int2* __restrict__ epair,
    const float* __restrict__ edge_attr, const float* __restrict__ W_edge,
    const float* __restrict__ P, float* __restrict__ m, int N) {
    const int j0 = (threadIdx.x & 31) * 4;
    float4 w[ED];
#pragma unroll
    for (int k = 0; k < ED; ++k)
        w[k] = *(const float4*)&W_edge[k * ND + j0];
    const int v = blockIdx.x * 8 + (threadIdx.x >> 5);
    int s = 0, t = 0;
    if (v < N) { s = base[v]; t = base[v + 1]; }
    float4 acc = {0.f, 0.f, 0.f, 0.f};

    int p = s;
    float4 eaA[8], eaB[8], pA, pB;
    int2 enN = make_int2(0, 0);
    if (p < t) {
        const int2 en0 = epair[p];
        seg_load(edge_attr, P, en0.x, en0.y, j0, eaA, pA);
    }
    if (p + 1 < t) enN = epair[p + 1];
    while (p + 1 < t) {
        seg_load(edge_attr, P, enN.x, enN.y, j0, eaB, pB);   // data p+1
        if (p + 2 < t) enN = epair[p + 2];                    // idx p+2
        seg_comp(eaA, pA, w, acc);                            // compute p
        ++p;
        if (p + 1 < t) {
            seg_load(edge_attr, P, enN.x, enN.y, j0, eaA, pA);
            if (p + 2 < t) enN = epair[p + 2];
            seg_comp(eaB, pB, w, acc);
            ++p;
        } else {
            seg_comp(eaB, pB, w, acc);
            ++p;
        }
    }
    if (p < t) seg_comp(eaA, pA, w, acc);
    if (v < N) *(float4*)&m[(size_t)v * ND + j0] = acc;
}

// ---------------------------------------------------------------------------
// out[r] = LayerNorm(C2[r] + m[r] @ W_bot) * lnw + lnb   (in-place on d_out).
// Same spill-safe structure as gemm128_kernel; C2 added in the epilogue.
// ---------------------------------------------------------------------------
__global__ __launch_bounds__(512, 4) void final_kernel(
    const float* __restrict__ C2, const float* __restrict__ m,
    const float* __restrict__ Wb, const float* __restrict__ lnw,
    const float* __restrict__ lnb, float* __restrict__ out, int N) {
    __shared__ float Ws[ND * ND];
    {
        float4* d = (float4*)Ws;
        const float4* s = (const float4*)Wb;
        for (int i = threadIdx.x; i < (ND * ND) / 4; i += 512) d[i] = s[i];
    }
    __syncthreads();
    const int slot = (int)(threadIdx.x >> 5);
    const int j0 = ((int)threadIdx.x & 31) * 4;
    const int rbase = blockIdx.x * 64 + slot * 4;
    const int r0 = (rbase + 0 < N) ? rbase + 0 : N - 1;
    const int r1 = (rbase + 1 < N) ? rbase + 1 : N - 1;
    const int r2 = (rbase + 2 < N) ? rbase + 2 : N - 1;
    const int r3 = (rbase + 3 < N) ? rbase + 3 : N - 1;
    const float* ap0 = m + (size_t)r0 * ND;
    const float* ap1 = m + (size_t)r1 * ND;
    const float* ap2 = m + (size_t)r2 * ND;
    const float* ap3 = m + (size_t)r3 * ND;
    float4 acc0 = {0,0,0,0}, acc1 = {0,0,0,0};
    float4 acc2 = {0,0,0,0}, acc3 = {0,0,0,0};
#pragma unroll 2
    for (int c = 0; c < 32; ++c) {
        const float4 a0 = *(const float4*)(ap0 + c * 4);
        const float4 a1 = *(const float4*)(ap1 + c * 4);
        const float4 a2 = *(const float4*)(ap2 + c * 4);
        const float4 a3 = *(const float4*)(ap3 + c * 4);
#pragma unroll
        for (int kk = 0; kk < 4; ++kk) {
            const float4 w = *(const float4*)&Ws[(c * 4 + kk) * ND + j0];
            const float x0 = ((const float*)&a0)[kk];
            const float x1 = ((const float*)&a1)[kk];
            const float x2 = ((const float*)&a2)[kk];
            const float x3 = ((const float*)&a3)[kk];
            acc0.x += x0 * w.x; acc0.y += x0 * w.y;
            acc0.z += x0 * w.z; acc0.w += x0 * w.w;
            acc1.x += x1 * w.x; acc1.y += x1 * w.y;
            acc1.z += x1 * w.z; acc1.w += x1 * w.w;
            acc2.x += x2 * w.x; acc2.y += x2 * w.y;
            acc2.z += x2 * w.z; acc2.w += x2 * w.w;
            acc3.x += x3 * w.x; acc3.y += x3 * w.y;
            acc3.z += x3 * w.z; acc3.w += x3 * w.w;
        }
    }
    const float4 w4 = *(const float4*)&lnw[j0];
    const float4 b4 = *(const float4*)&lnb[j0];
#define LN_ROW(ACC, RQ, VALID)                                               \
    {                                                                        \
        const float4 c2 = *(const float4*)&C2[(size_t)(RQ) * ND + j0];       \
        float4 h = {ACC.x + c2.x, ACC.y + c2.y, ACC.z + c2.z, ACC.w + c2.w}; \
        float sum = h.x + h.y + h.z + h.w;                                   \
        sum += __shfl_xor(sum, 16); sum += __shfl_xor(sum, 8);               \
        sum += __shfl_xor(sum, 4);  sum += __shfl_xor(sum, 2);               \
        sum += __shfl_xor(sum, 1);                                           \
        const float mean = sum * (1.f / ND);                                 \
        const float4 dd = {h.x - mean, h.y - mean, h.z - mean, h.w - mean};  \
        float qv = dd.x * dd.x + dd.y * dd.y + dd.z * dd.z + dd.w * dd.w;    \
        qv += __shfl_xor(qv, 16); qv += __shfl_xor(qv, 8);                   \
        qv += __shfl_xor(qv, 4);  qv += __shfl_xor(qv, 2);                   \
        qv += __shfl_xor(qv, 1);                                             \
        const float rstd = rsqrtf(qv * (1.f / ND) + LN_EPS);                 \
        if (VALID) {                                                         \
            float4 o;                                                        \
            o.x = dd.x * rstd * w4.x + b4.x;                                 \
            o.y = dd.y * rstd * w4.y + b4.y;                                 \
            o.z = dd.z * rstd * w4.z + b4.z;                                 \
            o.w = dd.w * rstd * w4.w + b4.w;                                 \
            *(float4*)&out[(size_t)(RQ) * ND + j0] = o;                      \
        }                                                                    \
    }
    LN_ROW(acc0, r0, rbase + 0 < N)
    LN_ROW(acc1, r1, rbase + 1 < N)
    LN_ROW(acc2, r2, rbase + 2 < N)
    LN_ROW(acc3, r3, rbase + 3 < N)
#undef LN_ROW
}

// ---------------------------------------------------------------------------
extern "C" void kernel_launch(void* const* d_in, const int* in_sizes, int n_in,
                              void* d_out, int out_size, void* d_ws, size_t ws_size,
                              hipStream_t stream) {
    const float*    node_attr = (const float*)d_in[0];
    const float*    edge_attr = (const float*)d_in[1];
    const unsigned* edge_idx  = (const unsigned*)d_in[2];
    const float*    W_node    = (const float*)d_in[3];
    const float*    W_center  = (const float*)d_in[4];
    const float*    W_concat  = (const float*)d_in[5];
    const float*    W_edge    = (const float*)d_in[6];
    const float*    lnw       = (const float*)d_in[7];
    const float*    lnb       = (const float*)d_in[8];
    float* out = (float*)d_out;

    const int N = in_sizes[0] / ND;   // 50000
    const int E = in_sizes[1] / ED;   // 800000

    char* ws = (char*)d_ws;
    float* wcc   = (float*)ws;                          // 16384 f
    float* P     = (float*)(ws + 65536);                // [N,128]
    float* m     = P + (size_t)N * ND;                  // [N,128]
    int*   ctr   = (int*)(m + (size_t)N * ND);          // [E]
    int*   ngh   = ctr + E;                             // [E]
    int2*  epair = (int2*)(ngh + E);                    // [E]
    int*   cnt   = (int*)(epair + E);                   // [N]
    int*   base  = cnt + N;                             // [N+1]
    int*   cur   = base + N + 1;                        // [N]

    hipMemsetAsync(cnt, 0, (size_t)N * sizeof(int), stream);
    conv_hist_kernel<<<512, 256, 0, stream>>>(edge_idx, ctr, ngh, cnt, E);
    scan_kernel<<<1, 1024, 0, stream>>>(cnt, base, cur, N);
    scatter_kernel<<<512, 256, 0, stream>>>(ctr, ngh, base, cur, epair, E);
    wcc_kernel<<<128, 128, 0, stream>>>(W_center, W_concat, wcc);
    gemm128_kernel<<<(N + 63) / 64, 512, 0, stream>>>(node_attr, W_node, P, N);
    gemm128_kernel<<<(N + 63) / 64, 512, 0, stream>>>(node_attr, wcc, out, N);
    seg_kernel<<<(N + 7) / 8, 256, 0, stream>>>(base, epair, edge_attr, W_edge,
                                                P, m, N);
    final_kernel<<<(N + 63) / 64, 512, 0, stream>>>(out, m, W_concat + ND * ND,
                                                    lnw, lnb, out, N);
}

// Round 6
// 638.536 us; speedup vs baseline: 6.1463x; 1.0148x over previous
//
#include <hip/hip_runtime.h>

#define ND 128   // node feature dim D
#define ED 32    // edge radial basis dim
#define LN_EPS 1e-5f

// ---------------------------------------------------------------------------
// Detect int64-vs-int32 edge_index, convert to int32 ctr/ngh, histogram ctr.
// ---------------------------------------------------------------------------
__global__ void conv_hist_kernel(const unsigned* __restrict__ raw,
                                 int* __restrict__ ctr, int* __restrict__ ngh,
                                 int* __restrict__ cnt, int E) {
    __shared__ int s_is64;
    if (threadIdx.x == 0) {
        unsigned acc = 0;
        for (int i = 1; i < 512; i += 2) acc |= raw[i];
        s_is64 = (acc == 0) ? 1 : 0;
    }
    __syncthreads();
    const int is64 = s_is64;
    const int tid = blockIdx.x * blockDim.x + threadIdx.x;
    const int stride = gridDim.x * blockDim.x;
    if (is64) {
        for (int e = tid; e < E; e += stride) {
            const int c = (int)raw[(size_t)2 * e];
            ctr[e] = c;
            ngh[e] = (int)raw[(size_t)2 * E + (size_t)2 * e];
            atomicAdd(&cnt[c], 1);
        }
    } else {
        for (int e = tid; e < E; e += stride) {
            const int c = (int)raw[e];
            ctr[e] = c;
            ngh[e] = (int)raw[(size_t)E + e];
            atomicAdd(&cnt[c], 1);
        }
    }
}

// ---------------------------------------------------------------------------
// Single-block exclusive scan over cnt[0..N) -> base[0..N]; zero cur[].
// ---------------------------------------------------------------------------
__global__ __launch_bounds__(1024) void scan_kernel(
    const int* __restrict__ cnt, int* __restrict__ base,
    int* __restrict__ cur, int N) {
    __shared__ int part[1024];
    const int tid = threadIdx.x;
    const int chunk = (N + 1023) >> 10;
    const int lo = tid * chunk;
    const int hi = min(lo + chunk, N);
    int s = 0;
    for (int i = lo; i < hi; ++i) { s += cnt[i]; cur[i] = 0; }
    part[tid] = s;
    __syncthreads();
    for (int off = 1; off < 1024; off <<= 1) {
        int v = 0;
        if (tid >= off) v = part[tid - off];
        __syncthreads();
        part[tid] += v;
        __syncthreads();
    }
    int excl = (tid > 0) ? part[tid - 1] : 0;
    for (int i = lo; i < hi; ++i) { base[i] = excl; excl += cnt[i]; }
    if (tid == 1023) base[N] = part[1023];
}

// ---------------------------------------------------------------------------
// Scatter edges into center-sorted order as int2 (edge_id, neighbor).
// ---------------------------------------------------------------------------
__global__ void scatter_kernel(const int* __restrict__ ctr,
                               const int* __restrict__ ngh,
                               const int* __restrict__ base,
                               int* __restrict__ cur,
                               int2* __restrict__ epair, int E) {
    const int tid = blockIdx.x * blockDim.x + threadIdx.x;
    const int stride = gridDim.x * blockDim.x;
    for (int e = tid; e < E; e += stride) {
        const int c = ctr[e];
        const int pos = base[c] + atomicAdd(&cur[c], 1);
        epair[pos] = make_int2(e, ngh[e]);
    }
}

// ---------------------------------------------------------------------------
// wcc = W_center_node @ W_concat[0:128, :]
// ---------------------------------------------------------------------------
__global__ void wcc_kernel(const float* __restrict__ Wc,
                           const float* __restrict__ Wcat,
                           float* __restrict__ wcc) {
    const int i = blockIdx.x;
    const int j = threadIdx.x;
    float acc = 0.f;
    for (int k = 0; k < ND; ++k)
        acc += Wc[i * ND + k] * Wcat[k * ND + j];
    wcc[i * ND + j] = acc;
}

// ---------------------------------------------------------------------------
// out[M,128] = A[M,128] @ W[128,128], fp32. (unchanged from round 5 — works)
// ---------------------------------------------------------------------------
__global__ __launch_bounds__(512, 4) void gemm128_kernel(
    const float* __restrict__ A, const float* __restrict__ W,
    float* __restrict__ out, int M) {
    __shared__ float Ws[ND * ND];
    {
        float4* d = (float4*)Ws;
        const float4* s = (const float4*)W;
        for (int i = threadIdx.x; i < (ND * ND) / 4; i += 512) d[i] = s[i];
    }
    __syncthreads();
    const int slot = (int)(threadIdx.x >> 5);    // 0..15
    const int j0 = ((int)threadIdx.x & 31) * 4;
    const int rbase = blockIdx.x * 64 + slot * 4;
    const int r0 = (rbase + 0 < M) ? rbase + 0 : M - 1;
    const int r1 = (rbase + 1 < M) ? rbase + 1 : M - 1;
    const int r2 = (rbase + 2 < M) ? rbase + 2 : M - 1;
    const int r3 = (rbase + 3 < M) ? rbase + 3 : M - 1;
    const float* ap0 = A + (size_t)r0 * ND;
    const float* ap1 = A + (size_t)r1 * ND;
    const float* ap2 = A + (size_t)r2 * ND;
    const float* ap3 = A + (size_t)r3 * ND;
    float4 acc0 = {0,0,0,0}, acc1 = {0,0,0,0};
    float4 acc2 = {0,0,0,0}, acc3 = {0,0,0,0};
#pragma unroll 2
    for (int c = 0; c < 32; ++c) {
        const float4 a0 = *(const float4*)(ap0 + c * 4);
        const float4 a1 = *(const float4*)(ap1 + c * 4);
        const float4 a2 = *(const float4*)(ap2 + c * 4);
        const float4 a3 = *(const float4*)(ap3 + c * 4);
#pragma unroll
        for (int kk = 0; kk < 4; ++kk) {
            const float4 w = *(const float4*)&Ws[(c * 4 + kk) * ND + j0];
            const float x0 = ((const float*)&a0)[kk];
            const float x1 = ((const float*)&a1)[kk];
            const float x2 = ((const float*)&a2)[kk];
            const float x3 = ((const float*)&a3)[kk];
            acc0.x += x0 * w.x; acc0.y += x0 * w.y;
            acc0.z += x0 * w.z; acc0.w += x0 * w.w;
            acc1.x += x1 * w.x; acc1.y += x1 * w.y;
            acc1.z += x1 * w.z; acc1.w += x1 * w.w;
            acc2.x += x2 * w.x; acc2.y += x2 * w.y;
            acc2.z += x2 * w.z; acc2.w += x2 * w.w;
            acc3.x += x3 * w.x; acc3.y += x3 * w.y;
            acc3.z += x3 * w.z; acc3.w += x3 * w.w;
        }
    }
    if (rbase + 0 < M) *(float4*)&out[(size_t)r0 * ND + j0] = acc0;
    if (rbase + 1 < M) *(float4*)&out[(size_t)r1 * ND + j0] = acc1;
    if (rbase + 2 < M) *(float4*)&out[(size_t)r2 * ND + j0] = acc2;
    if (rbase + 3 < M) *(float4*)&out[(size_t)r3 * ND + j0] = acc3;
}

// ---------------------------------------------------------------------------
// Segmented edge reduction v2: one FULL 64-lane wave per node, lane owns
// 2 cols (float2). W_edge = 32 x float2 = 64 VGPR (genuinely live).
// All loop conditions wave-uniform -> scalar branches, zero divergence.
// 2-edge double-buffer with 2-ahead epair prefetch. No atomics.
// ---------------------------------------------------------------------------
__device__ __forceinline__ void seg2_load(const float* __restrict__ edge_attr,
                                          const float* __restrict__ P,
                                          int e, int n, int j0,
                                          float4 (&ea)[8], float2& pr) {
    const float4* ea4 = (const float4*)(edge_attr + (size_t)e * ED);
#pragma unroll
    for (int i = 0; i < 8; ++i) ea[i] = ea4[i];     // broadcast loads
    pr = *(const float2*)&P[(size_t)n * ND + j0];    // coalesced across wave
}

__device__ __forceinline__ void seg2_comp(const float4 (&ea)[8],
                                          const float2& pr,
                                          const float2 (&w)[ED], float2& acc) {
    float2 r = {0.f, 0.f};
#pragma unroll
    for (int k = 0; k < ED; ++k) {
        const float a = ((const float*)ea)[k];       // static reg selection
        r.x += a * w[k].x;
        r.y += a * w[k].y;
    }
    acc.x += r.x * pr.x;
    acc.y += r.y * pr.y;
}

__global__ __launch_bounds__(256) void seg_kernel(
    const int* __restrict__ base, const int2* __restrict__ epair,
    const float* __restrict__ edge_attr, const float* __restrict__ W_edge,
    const float* __restrict__ P, float* __restrict__ m, int N) {
    const int j0 = ((int)threadIdx.x & 63) * 2;
    float2 w[ED];
#pragma unroll
    for (int k = 0; k < ED; ++k)
        w[k] = *(const float2*)&W_edge[k * ND + j0];
    const int v = blockIdx.x * 4 + ((int)threadIdx.x >> 6);
    if (v >= N) return;
    const int s = base[v], t = base[v + 1];   // wave-uniform
    float2 acc = {0.f, 0.f};

    int p = s;
    float4 eaA[8], eaB[8];
    float2 pA, pB;
    int2 eA = make_int2(0, 0), eB = make_int2(0, 0);
    if (t - p >= 1) eA = epair[p];
    if (t - p >= 2) eB = epair[p + 1];
    if (t - p >= 1) seg2_load(edge_attr, P, eA.x, eA.y, j0, eaA, pA);
    // invariant at loop head: eaA/pA hold data for p; eB holds epair[p+1]
    while (t - p >= 2) {
        seg2_load(edge_attr, P, eB.x, eB.y, j0, eaB, pB);   // data p+1
        if (t - p >= 3) eA = epair[p + 2];                   // idx p+2
        seg2_comp(eaA, pA, w, acc);                          // compute p
        if (t - p >= 3) {
            seg2_load(edge_attr, P, eA.x, eA.y, j0, eaA, pA); // data p+2
            if (t - p >= 4) eB = epair[p + 3];                // idx p+3
            seg2_comp(eaB, pB, w, acc);                       // compute p+1
            p += 2;
        } else {
            seg2_comp(eaB, pB, w, acc);                       // compute p+1
            p += 2;                                           // t-p==0, exit
        }
    }
    if (t - p == 1) seg2_comp(eaA, pA, w, acc);
    *(float2*)&m[(size_t)v * ND + j0] = acc;
}

// ---------------------------------------------------------------------------
// out[r] = LayerNorm(C2[r] + m[r] @ W_bot) * lnw + lnb  (unchanged — works)
// ---------------------------------------------------------------------------
__global__ __launch_bounds__(512, 4) void final_kernel(
    const float* __restrict__ C2, const float* __restrict__ m,
    const float* __restrict__ Wb, const float* __restrict__ lnw,
    const float* __restrict__ lnb, float* __restrict__ out, int N) {
    __shared__ float Ws[ND * ND];
    {
        float4* d = (float4*)Ws;
        const float4* s = (const float4*)Wb;
        for (int i = threadIdx.x; i < (ND * ND) / 4; i += 512) d[i] = s[i];
    }
    __syncthreads();
    const int slot = (int)(threadIdx.x >> 5);
    const int j0 = ((int)threadIdx.x & 31) * 4;
    const int rbase = blockIdx.x * 64 + slot * 4;
    const int r0 = (rbase + 0 < N) ? rbase + 0 : N - 1;
    const int r1 = (rbase + 1 < N) ? rbase + 1 : N - 1;
    const int r2 = (rbase + 2 < N) ? rbase + 2 : N - 1;
    const int r3 = (rbase + 3 < N) ? rbase + 3 : N - 1;
    const float* ap0 = m + (size_t)r0 * ND;
    const float* ap1 = m + (size_t)r1 * ND;
    const float* ap2 = m + (size_t)r2 * ND;
    const float* ap3 = m + (size_t)r3 * ND;
    float4 acc0 = {0,0,0,0}, acc1 = {0,0,0,0};
    float4 acc2 = {0,0,0,0}, acc3 = {0,0,0,0};
#pragma unroll 2
    for (int c = 0; c < 32; ++c) {
        const float4 a0 = *(const float4*)(ap0 + c * 4);
        const float4 a1 = *(const float4*)(ap1 + c * 4);
        const float4 a2 = *(const float4*)(ap2 + c * 4);
        const float4 a3 = *(const float4*)(ap3 + c * 4);
#pragma unroll
        for (int kk = 0; kk < 4; ++kk) {
            const float4 w = *(const float4*)&Ws[(c * 4 + kk) * ND + j0];
            const float x0 = ((const float*)&a0)[kk];
            const float x1 = ((const float*)&a1)[kk];
            const float x2 = ((const float*)&a2)[kk];
            const float x3 = ((const float*)&a3)[kk];
            acc0.x += x0 * w.x; acc0.y += x0 * w.y;
            acc0.z += x0 * w.z; acc0.w += x0 * w.w;
            acc1.x += x1 * w.x; acc1.y += x1 * w.y;
            acc1.z += x1 * w.z; acc1.w += x1 * w.w;
            acc2.x += x2 * w.x; acc2.y += x2 * w.y;
            acc2.z += x2 * w.z; acc2.w += x2 * w.w;
            acc3.x += x3 * w.x; acc3.y += x3 * w.y;
            acc3.z += x3 * w.z; acc3.w += x3 * w.w;
        }
    }
    const float4 w4 = *(const float4*)&lnw[j0];
    const float4 b4 = *(const float4*)&lnb[j0];
#define LN_ROW(ACC, RQ, VALID)                                               \
    {                                                                        \
        const float4 c2 = *(const float4*)&C2[(size_t)(RQ) * ND + j0];       \
        float4 h = {ACC.x + c2.x, ACC.y + c2.y, ACC.z + c2.z, ACC.w + c2.w}; \
        float sum = h.x + h.y + h.z + h.w;                                   \
        sum += __shfl_xor(sum, 16); sum += __shfl_xor(sum, 8);               \
        sum += __shfl_xor(sum, 4);  sum += __shfl_xor(sum, 2);               \
        sum += __shfl_xor(sum, 1);                                           \
        const float mean = sum * (1.f / ND);                                 \
        const float4 dd = {h.x - mean, h.y - mean, h.z - mean, h.w - mean};  \
        float qv = dd.x * dd.x + dd.y * dd.y + dd.z * dd.z + dd.w * dd.w;    \
        qv += __shfl_xor(qv, 16); qv += __shfl_xor(qv, 8);                   \
        qv += __shfl_xor(qv, 4);  qv += __shfl_xor(qv, 2);                   \
        qv += __shfl_xor(qv, 1);                                             \
        const float rstd = rsqrtf(qv * (1.f / ND) + LN_EPS);                 \
        if (VALID) {                                                         \
            float4 o;                                                        \
            o.x = dd.x * rstd * w4.x + b4.x;                                 \
            o.y = dd.y * rstd * w4.y + b4.y;                                 \
            o.z = dd.z * rstd * w4.z + b4.z;                                 \
            o.w = dd.w * rstd * w4.w + b4.w;                                 \
            *(float4*)&out[(size_t)(RQ) * ND + j0] = o;                      \
        }                                                                    \
    }
    LN_ROW(acc0, r0, rbase + 0 < N)
    LN_ROW(acc1, r1, rbase + 1 < N)
    LN_ROW(acc2, r2, rbase + 2 < N)
    LN_ROW(acc3, r3, rbase + 3 < N)
#undef LN_ROW
}

// ---------------------------------------------------------------------------
extern "C" void kernel_launch(void* const* d_in, const int* in_sizes, int n_in,
                              void* d_out, int out_size, void* d_ws, size_t ws_size,
                              hipStream_t stream) {
    const float*    node_attr = (const float*)d_in[0];
    const float*    edge_attr = (const float*)d_in[1];
    const unsigned* edge_idx  = (const unsigned*)d_in[2];
    const float*    W_node    = (const float*)d_in[3];
    const float*    W_center  = (const float*)d_in[4];
    const float*    W_concat  = (const float*)d_in[5];
    const float*    W_edge    = (const float*)d_in[6];
    const float*    lnw       = (const float*)d_in[7];
    const float*    lnb       = (const float*)d_in[8];
    float* out = (float*)d_out;

    const int N = in_sizes[0] / ND;   // 50000
    const int E = in_sizes[1] / ED;   // 800000

    char* ws = (char*)d_ws;
    float* wcc   = (float*)ws;                          // 16384 f
    float* P     = (float*)(ws + 65536);                // [N,128]
    float* m     = P + (size_t)N * ND;                  // [N,128]
    int*   ctr   = (int*)(m + (size_t)N * ND);          // [E]
    int*   ngh   = ctr + E;                             // [E]
    int2*  epair = (int2*)(ngh + E);                    // [E]
    int*   cnt   = (int*)(epair + E);                   // [N]
    int*   base  = cnt + N;                             // [N+1]
    int*   cur   = base + N + 1;                        // [N]

    hipMemsetAsync(cnt, 0, (size_t)N * sizeof(int), stream);
    conv_hist_kernel<<<512, 256, 0, stream>>>(edge_idx, ctr, ngh, cnt, E);
    scan_kernel<<<1, 1024, 0, stream>>>(cnt, base, cur, N);
    scatter_kernel<<<512, 256, 0, stream>>>(ctr, ngh, base, cur, epair, E);
    wcc_kernel<<<128, 128, 0, stream>>>(W_center, W_concat, wcc);
    gemm128_kernel<<<(N + 63) / 64, 512, 0, stream>>>(node_attr, W_node, P, N);
    gemm128_kernel<<<(N + 63) / 64, 512, 0, stream>>>(node_attr, wcc, out, N);
    seg_kernel<<<(N + 3) / 4, 256, 0, stream>>>(base, epair, edge_attr, W_edge,
                                                P, m, N);
    final_kernel<<<(N + 63) / 64, 512, 0, stream>>>(out, m, W_concat + ND * ND,
                                                    lnw, lnb, out, N);
}

// Round 7
// 473.952 us; speedup vs baseline: 8.2807x; 1.3473x over previous
//
#include <hip/hip_runtime.h>

#define ND 128   // node feature dim D
#define ED 32    // edge radial basis dim
#define LN_EPS 1e-5f

// ---------------------------------------------------------------------------
// Detect int64-vs-int32 edge_index, convert to int32 ctr/ngh, histogram ctr.
// ---------------------------------------------------------------------------
__global__ void conv_hist_kernel(const unsigned* __restrict__ raw,
                                 int* __restrict__ ctr, int* __restrict__ ngh,
                                 int* __restrict__ cnt, int E) {
    __shared__ int s_is64;
    if (threadIdx.x == 0) {
        unsigned acc = 0;
        for (int i = 1; i < 512; i += 2) acc |= raw[i];
        s_is64 = (acc == 0) ? 1 : 0;
    }
    __syncthreads();
    const int is64 = s_is64;
    const int tid = blockIdx.x * blockDim.x + threadIdx.x;
    const int stride = gridDim.x * blockDim.x;
    if (is64) {
        for (int e = tid; e < E; e += stride) {
            const int c = (int)raw[(size_t)2 * e];
            ctr[e] = c;
            ngh[e] = (int)raw[(size_t)2 * E + (size_t)2 * e];
            atomicAdd(&cnt[c], 1);
        }
    } else {
        for (int e = tid; e < E; e += stride) {
            const int c = (int)raw[e];
            ctr[e] = c;
            ngh[e] = (int)raw[(size_t)E + e];
            atomicAdd(&cnt[c], 1);
        }
    }
}

// ---------------------------------------------------------------------------
// Single-block exclusive scan over cnt[0..N) -> base[0..N]; zero cur[].
// ---------------------------------------------------------------------------
__global__ __launch_bounds__(1024) void scan_kernel(
    const int* __restrict__ cnt, int* __restrict__ base,
    int* __restrict__ cur, int N) {
    __shared__ int part[1024];
    const int tid = threadIdx.x;
    const int chunk = (N + 1023) >> 10;
    const int lo = tid * chunk;
    const int hi = min(lo + chunk, N);
    int s = 0;
    for (int i = lo; i < hi; ++i) { s += cnt[i]; cur[i] = 0; }
    part[tid] = s;
    __syncthreads();
    for (int off = 1; off < 1024; off <<= 1) {
        int v = 0;
        if (tid >= off) v = part[tid - off];
        __syncthreads();
        part[tid] += v;
        __syncthreads();
    }
    int excl = (tid > 0) ? part[tid - 1] : 0;
    for (int i = lo; i < hi; ++i) { base[i] = excl; excl += cnt[i]; }
    if (tid == 1023) base[N] = part[1023];
}

// ---------------------------------------------------------------------------
// Scatter edges into center-sorted order as int2 (edge_id, neighbor).
// ---------------------------------------------------------------------------
__global__ void scatter_kernel(const int* __restrict__ ctr,
                               const int* __restrict__ ngh,
                               const int* __restrict__ base,
                               int* __restrict__ cur,
                               int2* __restrict__ epair, int E) {
    const int tid = blockIdx.x * blockDim.x + threadIdx.x;
    const int stride = gridDim.x * blockDim.x;
    for (int e = tid; e < E; e += stride) {
        const int c = ctr[e];
        const int pos = base[c] + atomicAdd(&cur[c], 1);
        epair[pos] = make_int2(e, ngh[e]);
    }
}

// ---------------------------------------------------------------------------
// wcc = W_center_node @ W_concat[0:128, :]
// ---------------------------------------------------------------------------
__global__ void wcc_kernel(const float* __restrict__ Wc,
                           const float* __restrict__ Wcat,
                           float* __restrict__ wcc) {
    const int i = blockIdx.x;
    const int j = threadIdx.x;
    float acc = 0.f;
    for (int k = 0; k < ND; ++k)
        acc += Wc[i * ND + k] * Wcat[k * ND + j];
    wcc[i * ND + j] = acc;
}

// ---------------------------------------------------------------------------
// out[M,128] = A[M,128] @ W[128,128], fp32. (unchanged from round 5 — works)
// ---------------------------------------------------------------------------
__global__ __launch_bounds__(512, 4) void gemm128_kernel(
    const float* __restrict__ A, const float* __restrict__ W,
    float* __restrict__ out, int M) {
    __shared__ float Ws[ND * ND];
    {
        float4* d = (float4*)Ws;
        const float4* s = (const float4*)W;
        for (int i = threadIdx.x; i < (ND * ND) / 4; i += 512) d[i] = s[i];
    }
    __syncthreads();
    const int slot = (int)(threadIdx.x >> 5);    // 0..15
    const int j0 = ((int)threadIdx.x & 31) * 4;
    const int rbase = blockIdx.x * 64 + slot * 4;
    const int r0 = (rbase + 0 < M) ? rbase + 0 : M - 1;
    const int r1 = (rbase + 1 < M) ? rbase + 1 : M - 1;
    const int r2 = (rbase + 2 < M) ? rbase + 2 : M - 1;
    const int r3 = (rbase + 3 < M) ? rbase + 3 : M - 1;
    const float* ap0 = A + (size_t)r0 * ND;
    const float* ap1 = A + (size_t)r1 * ND;
    const float* ap2 = A + (size_t)r2 * ND;
    const float* ap3 = A + (size_t)r3 * ND;
    float4 acc0 = {0,0,0,0}, acc1 = {0,0,0,0};
    float4 acc2 = {0,0,0,0}, acc3 = {0,0,0,0};
#pragma unroll 2
    for (int c = 0; c < 32; ++c) {
        const float4 a0 = *(const float4*)(ap0 + c * 4);
        const float4 a1 = *(const float4*)(ap1 + c * 4);
        const float4 a2 = *(const float4*)(ap2 + c * 4);
        const float4 a3 = *(const float4*)(ap3 + c * 4);
#pragma unroll
        for (int kk = 0; kk < 4; ++kk) {
            const float4 w = *(const float4*)&Ws[(c * 4 + kk) * ND + j0];
            const float x0 = ((const float*)&a0)[kk];
            const float x1 = ((const float*)&a1)[kk];
            const float x2 = ((const float*)&a2)[kk];
            const float x3 = ((const float*)&a3)[kk];
            acc0.x += x0 * w.x; acc0.y += x0 * w.y;
            acc0.z += x0 * w.z; acc0.w += x0 * w.w;
            acc1.x += x1 * w.x; acc1.y += x1 * w.y;
            acc1.z += x1 * w.z; acc1.w += x1 * w.w;
            acc2.x += x2 * w.x; acc2.y += x2 * w.y;
            acc2.z += x2 * w.z; acc2.w += x2 * w.w;
            acc3.x += x3 * w.x; acc3.y += x3 * w.y;
            acc3.z += x3 * w.z; acc3.w += x3 * w.w;
        }
    }
    if (rbase + 0 < M) *(float4*)&out[(size_t)r0 * ND + j0] = acc0;
    if (rbase + 1 < M) *(float4*)&out[(size_t)r1 * ND + j0] = acc1;
    if (rbase + 2 < M) *(float4*)&out[(size_t)r2 * ND + j0] = acc2;
    if (rbase + 3 < M) *(float4*)&out[(size_t)r3 * ND + j0] = acc3;
}

// ---------------------------------------------------------------------------
// Segmented edge reduction v3: one 64-lane wave per node, lane owns 2 cols.
// Per edge: lane l loads ONE float ea[e*32 + (l&31)] (single coalesced
// 128-B line) and the k-broadcast is v_readlane -> SGPR feeding FMA
// directly (zero LDS ops, zero ds_bpermute — __shfl would use the DS pipe).
// W_edge = 32 x float2 = 64 VGPR, genuinely live now that ea buffers are
// 1 register each. Depth-2 data / 2-ahead index pipeline, wave-uniform
// control, no atomics, single coalesced row write.
// ---------------------------------------------------------------------------
__device__ __forceinline__ void seg3_load(const float* __restrict__ edge_attr,
                                          const float* __restrict__ P,
                                          int e, int n, int lane31, int j0,
                                          float& av, float2& pr) {
    av = edge_attr[(size_t)e * ED + lane31];          // 1 coalesced line/edge
    pr = *(const float2*)&P[(size_t)n * ND + j0];     // 512 B coalesced/wave
}

__device__ __forceinline__ void seg3_comp(float av, const float2& pr,
                                          const float2 (&w)[ED], float2& acc) {
    // 4 independent FMA chains (16 deep each) for ILP; combine at the end.
    float r0x = 0.f, r0y = 0.f, r1x = 0.f, r1y = 0.f;
#pragma unroll
    for (int k = 0; k < ED; k += 2) {
        const float a0 = __uint_as_float(
            __builtin_amdgcn_readlane(__float_as_uint(av), k));
        const float a1 = __uint_as_float(
            __builtin_amdgcn_readlane(__float_as_uint(av), k + 1));
        r0x += a0 * w[k].x;     r0y += a0 * w[k].y;
        r1x += a1 * w[k + 1].x; r1y += a1 * w[k + 1].y;
    }
    acc.x += (r0x + r1x) * pr.x;
    acc.y += (r0y + r1y) * pr.y;
}

__global__ __launch_bounds__(256) void seg_kernel(
    const int* __restrict__ base, const int2* __restrict__ epair,
    const float* __restrict__ edge_attr, const float* __restrict__ W_edge,
    const float* __restrict__ P, float* __restrict__ m, int N) {
    const int lane = (int)threadIdx.x & 63;
    const int lane31 = lane & 31;
    const int j0 = lane * 2;
    float2 w[ED];
#pragma unroll
    for (int k = 0; k < ED; ++k)
        w[k] = *(const float2*)&W_edge[k * ND + j0];
    const int v = blockIdx.x * 4 + ((int)threadIdx.x >> 6);
    if (v >= N) return;
    const int s = base[v], t = base[v + 1];   // wave-uniform
    float2 acc = {0.f, 0.f};

    int p = s;
    float avA = 0.f, avB = 0.f;
    float2 pA, pB;
    int2 eA = make_int2(0, 0), eB = make_int2(0, 0);
    if (t - p >= 1) eA = epair[p];
    if (t - p >= 2) eB = epair[p + 1];
    if (t - p >= 1) seg3_load(edge_attr, P, eA.x, eA.y, lane31, j0, avA, pA);
    // invariant at loop head: avA/pA hold data for p; eB holds epair[p+1]
    while (t - p >= 2) {
        seg3_load(edge_attr, P, eB.x, eB.y, lane31, j0, avB, pB);  // data p+1
        if (t - p >= 3) eA = epair[p + 2];                          // idx p+2
        seg3_comp(avA, pA, w, acc);                                 // comp p
        if (t - p >= 3) {
            seg3_load(edge_attr, P, eA.x, eA.y, lane31, j0, avA, pA); // p+2
            if (t - p >= 4) eB = epair[p + 3];                        // p+3
            seg3_comp(avB, pB, w, acc);                               // p+1
            p += 2;
        } else {
            seg3_comp(avB, pB, w, acc);                               // p+1
            p += 2;
        }
    }
    if (t - p == 1) seg3_comp(avA, pA, w, acc);
    *(float2*)&m[(size_t)v * ND + j0] = acc;
}

// ---------------------------------------------------------------------------
// out[r] = LayerNorm(C2[r] + m[r] @ W_bot) * lnw + lnb  (unchanged — works)
// ---------------------------------------------------------------------------
__global__ __launch_bounds__(512, 4) void final_kernel(
    const float* __restrict__ C2, const float* __restrict__ m,
    const float* __restrict__ Wb, const float* __restrict__ lnw,
    const float* __restrict__ lnb, float* __restrict__ out, int N) {
    __shared__ float Ws[ND * ND];
    {
        float4* d = (float4*)Ws;
        const float4* s = (const float4*)Wb;
        for (int i = threadIdx.x; i < (ND * ND) / 4; i += 512) d[i] = s[i];
    }
    __syncthreads();
    const int slot = (int)(threadIdx.x >> 5);
    const int j0 = ((int)threadIdx.x & 31) * 4;
    const int rbase = blockIdx.x * 64 + slot * 4;
    const int r0 = (rbase + 0 < N) ? rbase + 0 : N - 1;
    const int r1 = (rbase + 1 < N) ? rbase + 1 : N - 1;
    const int r2 = (rbase + 2 < N) ? rbase + 2 : N - 1;
    const int r3 = (rbase + 3 < N) ? rbase + 3 : N - 1;
    const float* ap0 = m + (size_t)r0 * ND;
    const float* ap1 = m + (size_t)r1 * ND;
    const float* ap2 = m + (size_t)r2 * ND;
    const float* ap3 = m + (size_t)r3 * ND;
    float4 acc0 = {0,0,0,0}, acc1 = {0,0,0,0};
    float4 acc2 = {0,0,0,0}, acc3 = {0,0,0,0};
#pragma unroll 2
    for (int c = 0; c < 32; ++c) {
        const float4 a0 = *(const float4*)(ap0 + c * 4);
        const float4 a1 = *(const float4*)(ap1 + c * 4);
        const float4 a2 = *(const float4*)(ap2 + c * 4);
        const float4 a3 = *(const float4*)(ap3 + c * 4);
#pragma unroll
        for (int kk = 0; kk < 4; ++kk) {
            const float4 w = *(const float4*)&Ws[(c * 4 + kk) * ND + j0];
            const float x0 = ((const float*)&a0)[kk];
            const float x1 = ((const float*)&a1)[kk];
            const float x2 = ((const float*)&a2)[kk];
            const float x3 = ((const float*)&a3)[kk];
            acc0.x += x0 * w.x; acc0.y += x0 * w.y;
            acc0.z += x0 * w.z; acc0.w += x0 * w.w;
            acc1.x += x1 * w.x; acc1.y += x1 * w.y;
            acc1.z += x1 * w.z; acc1.w += x1 * w.w;
            acc2.x += x2 * w.x; acc2.y += x2 * w.y;
            acc2.z += x2 * w.z; acc2.w += x2 * w.w;
            acc3.x += x3 * w.x; acc3.y += x3 * w.y;
            acc3.z += x3 * w.z; acc3.w += x3 * w.w;
        }
    }
    const float4 w4 = *(const float4*)&lnw[j0];
    const float4 b4 = *(const float4*)&lnb[j0];
#define LN_ROW(ACC, RQ, VALID)                                               \
    {                                                                        \
        const float4 c2 = *(const float4*)&C2[(size_t)(RQ) * ND + j0];       \
        float4 h = {ACC.x + c2.x, ACC.y + c2.y, ACC.z + c2.z, ACC.w + c2.w}; \
        float sum = h.x + h.y + h.z + h.w;                                   \
        sum += __shfl_xor(sum, 16); sum += __shfl_xor(sum, 8);               \
        sum += __shfl_xor(sum, 4);  sum += __shfl_xor(sum, 2);               \
        sum += __shfl_xor(sum, 1);                                           \
        const float mean = sum * (1.f / ND);                                 \
        const float4 dd = {h.x - mean, h.y - mean, h.z - mean, h.w - mean};  \
        float qv = dd.x * dd.x + dd.y * dd.y + dd.z * dd.z + dd.w * dd.w;    \
        qv += __shfl_xor(qv, 16); qv += __shfl_xor(qv, 8);                   \
        qv += __shfl_xor(qv, 4);  qv += __shfl_xor(qv, 2);                   \
        qv += __shfl_xor(qv, 1);                                             \
        const float rstd = rsqrtf(qv * (1.f / ND) + LN_EPS);                 \
        if (VALID) {                                                         \
            float4 o;                                                        \
            o.x = dd.x * rstd * w4.x + b4.x;                                 \
            o.y = dd.y * rstd * w4.y + b4.y;                                 \
            o.z = dd.z * rstd * w4.z + b4.z;                                 \
            o.w = dd.w * rstd * w4.w + b4.w;                                 \
            *(float4*)&out[(size_t)(RQ) * ND + j0] = o;                      \
        }                                                                    \
    }
    LN_ROW(acc0, r0, rbase + 0 < N)
    LN_ROW(acc1, r1, rbase + 1 < N)
    LN_ROW(acc2, r2, rbase + 2 < N)
    LN_ROW(acc3, r3, rbase + 3 < N)
#undef LN_ROW
}

// ---------------------------------------------------------------------------
extern "C" void kernel_launch(void* const* d_in, const int* in_sizes, int n_in,
                              void* d_out, int out_size, void* d_ws, size_t ws_size,
                              hipStream_t stream) {
    const float*    node_attr = (const float*)d_in[0];
    const float*    edge_attr = (const float*)d_in[1];
    const unsigned* edge_idx  = (const unsigned*)d_in[2];
    const float*    W_node    = (const float*)d_in[3];
    const float*    W_center  = (const float*)d_in[4];
    const float*    W_concat  = (const float*)d_in[5];
    const float*    W_edge    = (const float*)d_in[6];
    const float*    lnw       = (const float*)d_in[7];
    const float*    lnb       = (const float*)d_in[8];
    float* out = (float*)d_out;

    const int N = in_sizes[0] / ND;   // 50000
    const int E = in_sizes[1] / ED;   // 800000

    char* ws = (char*)d_ws;
    float* wcc   = (float*)ws;                          // 16384 f
    float* P     = (float*)(ws + 65536);                // [N,128]
    float* m     = P + (size_t)N * ND;                  // [N,128]
    int*   ctr   = (int*)(m + (size_t)N * ND);          // [E]
    int*   ngh   = ctr + E;                             // [E]
    int2*  epair = (int2*)(ngh + E);                    // [E]
    int*   cnt   = (int*)(epair + E);                   // [N]
    int*   base  = cnt + N;                             // [N+1]
    int*   cur   = base + N + 1;                        // [N]

    hipMemsetAsync(cnt, 0, (size_t)N * sizeof(int), stream);
    conv_hist_kernel<<<512, 256, 0, stream>>>(edge_idx, ctr, ngh, cnt, E);
    scan_kernel<<<1, 1024, 0, stream>>>(cnt, base, cur, N);
    scatter_kernel<<<512, 256, 0, stream>>>(ctr, ngh, base, cur, epair, E);
    wcc_kernel<<<128, 128, 0, stream>>>(W_center, W_concat, wcc);
    gemm128_kernel<<<(N + 63) / 64, 512, 0, stream>>>(node_attr, W_node, P, N);
    gemm128_kernel<<<(N + 63) / 64, 512, 0, stream>>>(node_attr, wcc, out, N);
    seg_kernel<<<(N + 3) / 4, 256, 0, stream>>>(base, epair, edge_attr, W_edge,
                                                P, m, N);
    final_kernel<<<(N + 63) / 64, 512, 0, stream>>>(out, m, W_concat + ND * ND,
                                                    lnw, lnb, out, N);
}

// Round 8
// 435.193 us; speedup vs baseline: 9.0182x; 1.0891x over previous
//
#include <hip/hip_runtime.h>

#define ND 128   // node feature dim D
#define ED 32    // edge radial basis dim
#define LN_EPS 1e-5f

// ---------------------------------------------------------------------------
// Detect int64-vs-int32 edge_index, convert to int32 ctr/ngh, histogram ctr.
// ---------------------------------------------------------------------------
__global__ void conv_hist_kernel(const unsigned* __restrict__ raw,
                                 int* __restrict__ ctr, int* __restrict__ ngh,
                                 int* __restrict__ cnt, int E) {
    __shared__ int s_is64;
    if (threadIdx.x == 0) {
        unsigned acc = 0;
        for (int i = 1; i < 512; i += 2) acc |= raw[i];
        s_is64 = (acc == 0) ? 1 : 0;
    }
    __syncthreads();
    const int is64 = s_is64;
    const int tid = blockIdx.x * blockDim.x + threadIdx.x;
    const int stride = gridDim.x * blockDim.x;
    if (is64) {
        for (int e = tid; e < E; e += stride) {
            const int c = (int)raw[(size_t)2 * e];
            ctr[e] = c;
            ngh[e] = (int)raw[(size_t)2 * E + (size_t)2 * e];
            atomicAdd(&cnt[c], 1);
        }
    } else {
        for (int e = tid; e < E; e += stride) {
            const int c = (int)raw[e];
            ctr[e] = c;
            ngh[e] = (int)raw[(size_t)E + e];
            atomicAdd(&cnt[c], 1);
        }
    }
}

// ---------------------------------------------------------------------------
// Single-block exclusive scan over cnt[0..N) -> base[0..N]; zero cur[].
// ---------------------------------------------------------------------------
__global__ __launch_bounds__(1024) void scan_kernel(
    const int* __restrict__ cnt, int* __restrict__ base,
    int* __restrict__ cur, int N) {
    __shared__ int part[1024];
    const int tid = threadIdx.x;
    const int chunk = (N + 1023) >> 10;
    const int lo = tid * chunk;
    const int hi = min(lo + chunk, N);
    int s = 0;
    for (int i = lo; i < hi; ++i) { s += cnt[i]; cur[i] = 0; }
    part[tid] = s;
    __syncthreads();
    for (int off = 1; off < 1024; off <<= 1) {
        int v = 0;
        if (tid >= off) v = part[tid - off];
        __syncthreads();
        part[tid] += v;
        __syncthreads();
    }
    int excl = (tid > 0) ? part[tid - 1] : 0;
    for (int i = lo; i < hi; ++i) { base[i] = excl; excl += cnt[i]; }
    if (tid == 1023) base[N] = part[1023];
}

// ---------------------------------------------------------------------------
// Scatter edges into center-sorted order as int2 (edge_id, neighbor).
// ---------------------------------------------------------------------------
__global__ void scatter_kernel(const int* __restrict__ ctr,
                               const int* __restrict__ ngh,
                               const int* __restrict__ base,
                               int* __restrict__ cur,
                               int2* __restrict__ epair, int E) {
    const int tid = blockIdx.x * blockDim.x + threadIdx.x;
    const int stride = gridDim.x * blockDim.x;
    for (int e = tid; e < E; e += stride) {
        const int c = ctr[e];
        const int pos = base[c] + atomicAdd(&cur[c], 1);
        epair[pos] = make_int2(e, ngh[e]);
    }
}

// ---------------------------------------------------------------------------
// wcc = W_center_node @ W_concat[0:128, :]
// ---------------------------------------------------------------------------
__global__ void wcc_kernel(const float* __restrict__ Wc,
                           const float* __restrict__ Wcat,
                           float* __restrict__ wcc) {
    const int i = blockIdx.x;
    const int j = threadIdx.x;
    float acc = 0.f;
    for (int k = 0; k < ND; ++k)
        acc += Wc[i * ND + k] * Wcat[k * ND + j];
    wcc[i * ND + j] = acc;
}

// ---------------------------------------------------------------------------
// out[M,128] = A[M,128] @ W[128,128], fp32. (unchanged from round 5 — works)
// ---------------------------------------------------------------------------
__global__ __launch_bounds__(512, 4) void gemm128_kernel(
    const float* __restrict__ A, const float* __restrict__ W,
    float* __restrict__ out, int M) {
    __shared__ float Ws[ND * ND];
    {
        float4* d = (float4*)Ws;
        const float4* s = (const float4*)W;
        for (int i = threadIdx.x; i < (ND * ND) / 4; i += 512) d[i] = s[i];
    }
    __syncthreads();
    const int slot = (int)(threadIdx.x >> 5);    // 0..15
    const int j0 = ((int)threadIdx.x & 31) * 4;
    const int rbase = blockIdx.x * 64 + slot * 4;
    const int r0 = (rbase + 0 < M) ? rbase + 0 : M - 1;
    const int r1 = (rbase + 1 < M) ? rbase + 1 : M - 1;
    const int r2 = (rbase + 2 < M) ? rbase + 2 : M - 1;
    const int r3 = (rbase + 3 < M) ? rbase + 3 : M - 1;
    const float* ap0 = A + (size_t)r0 * ND;
    const float* ap1 = A + (size_t)r1 * ND;
    const float* ap2 = A + (size_t)r2 * ND;
    const float* ap3 = A + (size_t)r3 * ND;
    float4 acc0 = {0,0,0,0}, acc1 = {0,0,0,0};
    float4 acc2 = {0,0,0,0}, acc3 = {0,0,0,0};
#pragma unroll 2
    for (int c = 0; c < 32; ++c) {
        const float4 a0 = *(const float4*)(ap0 + c * 4);
        const float4 a1 = *(const float4*)(ap1 + c * 4);
        const float4 a2 = *(const float4*)(ap2 + c * 4);
        const float4 a3 = *(const float4*)(ap3 + c * 4);
#pragma unroll
        for (int kk = 0; kk < 4; ++kk) {
            const float4 w = *(const float4*)&Ws[(c * 4 + kk) * ND + j0];
            const float x0 = ((const float*)&a0)[kk];
            const float x1 = ((const float*)&a1)[kk];
            const float x2 = ((const float*)&a2)[kk];
            const float x3 = ((const float*)&a3)[kk];
            acc0.x += x0 * w.x; acc0.y += x0 * w.y;
            acc0.z += x0 * w.z; acc0.w += x0 * w.w;
            acc1.x += x1 * w.x; acc1.y += x1 * w.y;
            acc1.z += x1 * w.z; acc1.w += x1 * w.w;
            acc2.x += x2 * w.x; acc2.y += x2 * w.y;
            acc2.z += x2 * w.z; acc2.w += x2 * w.w;
            acc3.x += x3 * w.x; acc3.y += x3 * w.y;
            acc3.z += x3 * w.z; acc3.w += x3 * w.w;
        }
    }
    if (rbase + 0 < M) *(float4*)&out[(size_t)r0 * ND + j0] = acc0;
    if (rbase + 1 < M) *(float4*)&out[(size_t)r1 * ND + j0] = acc1;
    if (rbase + 2 < M) *(float4*)&out[(size_t)r2 * ND + j0] = acc2;
    if (rbase + 3 < M) *(float4*)&out[(size_t)r3 * ND + j0] = acc3;
}

// ---------------------------------------------------------------------------
// Segmented edge reduction v4: one 64-lane wave per node (grid-strided over
// nodes to avoid wave churn). ea row is WAVE-UNIFORM -> load it into SGPRs
// with s_load_dwordx16 (scalar pipe, parallel to VALU); the k-broadcast is
// then a free SGPR operand on v_fmac — zero readlanes, zero DS ops, zero
// per-edge VMEM for ea. Two edges per lgkmcnt(0) wait (SMEM returns may be
// out-of-order -> no partial waits). P float2 loads stay vector (coalesced),
// compiler-managed vmcnt. sched_barrier(0) after the wait per guide rule #18.
// ---------------------------------------------------------------------------
typedef __attribute__((ext_vector_type(16))) int ivec16;

__device__ __forceinline__ void sload_ea(const float* p, ivec16& lo, ivec16& hi) {
    asm volatile("s_load_dwordx16 %0, %2, 0x0\n\t"
                 "s_load_dwordx16 %1, %2, 0x40"
                 : "=&s"(lo), "=&s"(hi)
                 : "s"(p));
}

__device__ __forceinline__ void seg4_fma(const ivec16& lo, const ivec16& hi,
                                         const float2& pr,
                                         const float2 (&w)[ED], float2& acc) {
    float r0x = 0.f, r0y = 0.f, r1x = 0.f, r1y = 0.f;
#pragma unroll
    for (int k = 0; k < 16; k += 2) {
        const float a0 = __int_as_float(lo[k]);
        const float a1 = __int_as_float(lo[k + 1]);
        r0x += a0 * w[k].x;     r0y += a0 * w[k].y;
        r1x += a1 * w[k + 1].x; r1y += a1 * w[k + 1].y;
    }
#pragma unroll
    for (int k = 0; k < 16; k += 2) {
        const float a0 = __int_as_float(hi[k]);
        const float a1 = __int_as_float(hi[k + 1]);
        r0x += a0 * w[16 + k].x;     r0y += a0 * w[16 + k].y;
        r1x += a1 * w[16 + k + 1].x; r1y += a1 * w[16 + k + 1].y;
    }
    acc.x += (r0x + r1x) * pr.x;
    acc.y += (r0y + r1y) * pr.y;
}

__global__ __launch_bounds__(256) void seg_kernel(
    const int* __restrict__ base, const int2* __restrict__ epair,
    const float* __restrict__ edge_attr, const float* __restrict__ W_edge,
    const float* __restrict__ P, float* __restrict__ m, int N) {
    const int lane = (int)threadIdx.x & 63;
    const int j0 = lane * 2;
    float2 w[ED];
#pragma unroll
    for (int k = 0; k < ED; ++k)
        w[k] = *(const float2*)&W_edge[k * ND + j0];
    const int wid = blockIdx.x * 4 + ((int)threadIdx.x >> 6);
    const int wstride = gridDim.x * 4;
    for (int v = wid; v < N; v += wstride) {
        const int s = base[v], t = base[v + 1];   // wave-uniform
        float2 acc = {0.f, 0.f};
        int p = s;
        while (t - p >= 2) {
            const int2 ep0 = epair[p];
            const int2 ep1 = epair[p + 1];
            const int e0 = __builtin_amdgcn_readfirstlane(ep0.x);
            const int n0 = __builtin_amdgcn_readfirstlane(ep0.y);
            const int e1 = __builtin_amdgcn_readfirstlane(ep1.x);
            const int n1 = __builtin_amdgcn_readfirstlane(ep1.y);
            ivec16 lo0, hi0, lo1, hi1;
            sload_ea(edge_attr + (size_t)e0 * ED, lo0, hi0);
            sload_ea(edge_attr + (size_t)e1 * ED, lo1, hi1);
            const float2 pr0 = *(const float2*)&P[(size_t)n0 * ND + j0];
            const float2 pr1 = *(const float2*)&P[(size_t)n1 * ND + j0];
            asm volatile("s_waitcnt lgkmcnt(0)" ::: "memory");
            __builtin_amdgcn_sched_barrier(0);
            seg4_fma(lo0, hi0, pr0, w, acc);
            seg4_fma(lo1, hi1, pr1, w, acc);
            p += 2;
        }
        if (t - p == 1) {
            const int2 ep0 = epair[p];
            const int e0 = __builtin_amdgcn_readfirstlane(ep0.x);
            const int n0 = __builtin_amdgcn_readfirstlane(ep0.y);
            ivec16 lo0, hi0;
            sload_ea(edge_attr + (size_t)e0 * ED, lo0, hi0);
            const float2 pr0 = *(const float2*)&P[(size_t)n0 * ND + j0];
            asm volatile("s_waitcnt lgkmcnt(0)" ::: "memory");
            __builtin_amdgcn_sched_barrier(0);
            seg4_fma(lo0, hi0, pr0, w, acc);
        }
        *(float2*)&m[(size_t)v * ND + j0] = acc;
    }
}

// ---------------------------------------------------------------------------
// out[r] = LayerNorm(C2[r] + m[r] @ W_bot) * lnw + lnb  (unchanged — works)
// ---------------------------------------------------------------------------
__global__ __launch_bounds__(512, 4) void final_kernel(
    const float* __restrict__ C2, const float* __restrict__ m,
    const float* __restrict__ Wb, const float* __restrict__ lnw,
    const float* __restrict__ lnb, float* __restrict__ out, int N) {
    __shared__ float Ws[ND * ND];
    {
        float4* d = (float4*)Ws;
        const float4* s = (const float4*)Wb;
        for (int i = threadIdx.x; i < (ND * ND) / 4; i += 512) d[i] = s[i];
    }
    __syncthreads();
    const int slot = (int)(threadIdx.x >> 5);
    const int j0 = ((int)threadIdx.x & 31) * 4;
    const int rbase = blockIdx.x * 64 + slot * 4;
    const int r0 = (rbase + 0 < N) ? rbase + 0 : N - 1;
    const int r1 = (rbase + 1 < N) ? rbase + 1 : N - 1;
    const int r2 = (rbase + 2 < N) ? rbase + 2 : N - 1;
    const int r3 = (rbase + 3 < N) ? rbase + 3 : N - 1;
    const float* ap0 = m + (size_t)r0 * ND;
    const float* ap1 = m + (size_t)r1 * ND;
    const float* ap2 = m + (size_t)r2 * ND;
    const float* ap3 = m + (size_t)r3 * ND;
    float4 acc0 = {0,0,0,0}, acc1 = {0,0,0,0};
    float4 acc2 = {0,0,0,0}, acc3 = {0,0,0,0};
#pragma unroll 2
    for (int c = 0; c < 32; ++c) {
        const float4 a0 = *(const float4*)(ap0 + c * 4);
        const float4 a1 = *(const float4*)(ap1 + c * 4);
        const float4 a2 = *(const float4*)(ap2 + c * 4);
        const float4 a3 = *(const float4*)(ap3 + c * 4);
#pragma unroll
        for (int kk = 0; kk < 4; ++kk) {
            const float4 w = *(const float4*)&Ws[(c * 4 + kk) * ND + j0];
            const float x0 = ((const float*)&a0)[kk];
            const float x1 = ((const float*)&a1)[kk];
            const float x2 = ((const float*)&a2)[kk];
            const float x3 = ((const float*)&a3)[kk];
            acc0.x += x0 * w.x; acc0.y += x0 * w.y;
            acc0.z += x0 * w.z; acc0.w += x0 * w.w;
            acc1.x += x1 * w.x; acc1.y += x1 * w.y;
            acc1.z += x1 * w.z; acc1.w += x1 * w.w;
            acc2.x += x2 * w.x; acc2.y += x2 * w.y;
            acc2.z += x2 * w.z; acc2.w += x2 * w.w;
            acc3.x += x3 * w.x; acc3.y += x3 * w.y;
            acc3.z += x3 * w.z; acc3.w += x3 * w.w;
        }
    }
    const float4 w4 = *(const float4*)&lnw[j0];
    const float4 b4 = *(const float4*)&lnb[j0];
#define LN_ROW(ACC, RQ, VALID)                                               \
    {                                                                        \
        const float4 c2 = *(const float4*)&C2[(size_t)(RQ) * ND + j0];       \
        float4 h = {ACC.x + c2.x, ACC.y + c2.y, ACC.z + c2.z, ACC.w + c2.w}; \
        float sum = h.x + h.y + h.z + h.w;                                   \
        sum += __shfl_xor(sum, 16); sum += __shfl_xor(sum, 8);               \
        sum += __shfl_xor(sum, 4);  sum += __shfl_xor(sum, 2);               \
        sum += __shfl_xor(sum, 1);                                           \
        const float mean = sum * (1.f / ND);                                 \
        const float4 dd = {h.x - mean, h.y - mean, h.z - mean, h.w - mean};  \
        float qv = dd.x * dd.x + dd.y * dd.y + dd.z * dd.z + dd.w * dd.w;    \
        qv += __shfl_xor(qv, 16); qv += __shfl_xor(qv, 8);                   \
        qv += __shfl_xor(qv, 4);  qv += __shfl_xor(qv, 2);                   \
        qv += __shfl_xor(qv, 1);                                             \
        const float rstd = rsqrtf(qv * (1.f / ND) + LN_EPS);                 \
        if (VALID) {                                                         \
            float4 o;                                                        \
            o.x = dd.x * rstd * w4.x + b4.x;                                 \
            o.y = dd.y * rstd * w4.y + b4.y;                                 \
            o.z = dd.z * rstd * w4.z + b4.z;                                 \
            o.w = dd.w * rstd * w4.w + b4.w;                                 \
            *(float4*)&out[(size_t)(RQ) * ND + j0] = o;                      \
        }                                                                    \
    }
    LN_ROW(acc0, r0, rbase + 0 < N)
    LN_ROW(acc1, r1, rbase + 1 < N)
    LN_ROW(acc2, r2, rbase + 2 < N)
    LN_ROW(acc3, r3, rbase + 3 < N)
#undef LN_ROW
}

// ---------------------------------------------------------------------------
extern "C" void kernel_launch(void* const* d_in, const int* in_sizes, int n_in,
                              void* d_out, int out_size, void* d_ws, size_t ws_size,
                              hipStream_t stream) {
    const float*    node_attr = (const float*)d_in[0];
    const float*    edge_attr = (const float*)d_in[1];
    const unsigned* edge_idx  = (const unsigned*)d_in[2];
    const float*    W_node    = (const float*)d_in[3];
    const float*    W_center  = (const float*)d_in[4];
    const float*    W_concat  = (const float*)d_in[5];
    const float*    W_edge    = (const float*)d_in[6];
    const float*    lnw       = (const float*)d_in[7];
    const float*    lnb       = (const float*)d_in[8];
    float* out = (float*)d_out;

    const int N = in_sizes[0] / ND;   // 50000
    const int E = in_sizes[1] / ED;   // 800000

    char* ws = (char*)d_ws;
    float* wcc   = (float*)ws;                          // 16384 f
    float* P     = (float*)(ws + 65536);                // [N,128]
    float* m     = P + (size_t)N * ND;                  // [N,128]
    int*   ctr   = (int*)(m + (size_t)N * ND);          // [E]
    int*   ngh   = ctr + E;                             // [E]
    int2*  epair = (int2*)(ngh + E);                    // [E]
    int*   cnt   = (int*)(epair + E);                   // [N]
    int*   base  = cnt + N;                             // [N+1]
    int*   cur   = base + N + 1;                        // [N]

    hipMemsetAsync(cnt, 0, (size_t)N * sizeof(int), stream);
    conv_hist_kernel<<<512, 256, 0, stream>>>(edge_idx, ctr, ngh, cnt, E);
    scan_kernel<<<1, 1024, 0, stream>>>(cnt, base, cur, N);
    scatter_kernel<<<512, 256, 0, stream>>>(ctr, ngh, base, cur, epair, E);
    wcc_kernel<<<128, 128, 0, stream>>>(W_center, W_concat, wcc);
    gemm128_kernel<<<(N + 63) / 64, 512, 0, stream>>>(node_attr, W_node, P, N);
    gemm128_kernel<<<(N + 63) / 64, 512, 0, stream>>>(node_attr, wcc, out, N);
    seg_kernel<<<2048, 256, 0, stream>>>(base, epair, edge_attr, W_edge,
                                         P, m, N);
    final_kernel<<<(N + 63) / 64, 512, 0, stream>>>(out, m, W_concat + ND * ND,
                                                    lnw, lnb, out, N);
}